// Round 14
// baseline (1147.958 us; speedup 1.0000x reference)
//
#include <hip/hip_runtime.h>
#include <cstddef>
#include <cstdint>

#define NPTS 2048

typedef short bf16x8 __attribute__((ext_vector_type(8)));
typedef float f32x4 __attribute__((ext_vector_type(4)));

__device__ __forceinline__ unsigned short f2bf(float f) {
  unsigned u = __builtin_bit_cast(unsigned, f);
  unsigned r = u + 0x7fffu + ((u >> 16) & 1u);  // RNE (finite inputs)
  return (unsigned short)(r >> 16);
}
__device__ __forceinline__ float bf2f(unsigned short s) {
  unsigned u = ((unsigned)s) << 16;
  return __builtin_bit_cast(float, u);
}
// float -> order-preserving u32 (handles negatives)
__device__ __forceinline__ unsigned f2sort(float f) {
  unsigned u = __builtin_bit_cast(unsigned, f);
  return u ^ (unsigned)(((int)u >> 31) | 0x80000000);
}

// sorted-4 pool insert (ascending); keys unique
__device__ __forceinline__ void pool_insert(uint64_t k, uint64_t& s0, uint64_t& s1,
                                            uint64_t& s2, uint64_t& s3) {
  s3 = k < s3 ? k : s3;
  uint64_t t;
  t = s2 < s3 ? s2 : s3; s3 = s2 < s3 ? s3 : s2; s2 = t;
  t = s1 < s2 ? s1 : s2; s2 = s1 < s2 ? s2 : s1; s1 = t;
  t = s0 < s1 ? s0 : s1; s1 = s0 < s1 ? s1 : s0; s0 = t;
}

// branchless wave-wide u64 min
__device__ __forceinline__ uint64_t wave_min_u64(uint64_t k) {
#pragma unroll
  for (int s = 1; s < 64; s <<= 1) {
    uint64_t ok = __shfl_xor((unsigned long long)k, s, 64);
    k = ok < k ? ok : k;
  }
  return k;
}

__device__ __forceinline__ int mbcnt64(unsigned long long m) {
  return __builtin_amdgcn_mbcnt_hi((unsigned)(m >> 32),
                                   __builtin_amdgcn_mbcnt_lo((unsigned)m, 0));
}

// ---------------------------------------------------------------- knn1 + cov (1 query per wave)
__global__ __launch_bounds__(256) void k_knn1_cov(const float* __restrict__ x,
                                                  float* __restrict__ h0) {
  const int b = blockIdx.y;
  const int tid = threadIdx.x;
  const int lane = tid & 63;
  const int w = tid >> 6;
  __shared__ float4 xsq[NPTS];
  const float* xb = x + (size_t)b * NPTS * 3;
  for (int i = tid; i < NPTS; i += 256) {
    float a0 = xb[3 * i], a1 = xb[3 * i + 1], a2 = xb[3 * i + 2];
    xsq[i] = make_float4(a0, a1, a2, fmaf(a0, a0, fmaf(a1, a1, a2 * a2)));
  }
  __syncthreads();
  const int nq = blockIdx.x * 4 + w;
  const float4 q4 = xsq[nq];
  const float sqq = q4.w;
  float d[32];
  uint64_t s0 = ~0ull, s1 = ~0ull, s2 = ~0ull, s3 = ~0ull;
#pragma unroll
  for (int j = 0; j < 32; ++j) {
    float4 v = xsq[j * 64 + lane];
    float dot = q4.x * v.x;
    dot = fmaf(q4.y, v.y, dot);
    dot = fmaf(q4.z, v.z, dot);
    float dd = fmaf(-2.f, dot, sqq + v.w);
    d[j] = dd;
    uint64_t k = ((uint64_t)f2sort(dd) << 32) | (unsigned)(j * 64 + lane);
    pool_insert(k, s0, s1, s2, s3);
  }
  int widx[16];
  int cnt = 0;
#pragma unroll
  for (int r = 0; r < 16; ++r) {
    uint64_t kmin = wave_min_u64(s0);
    widx[r] = (int)(unsigned)kmin;
    bool ex = (s0 == kmin);
    cnt += ex ? 1 : 0;
    s0 = ex ? s1 : s0; s1 = ex ? s2 : s1; s2 = ex ? s3 : s2; s3 = ex ? ~0ull : s3;
  }
  if (__ballot(cnt == 4) != 0ull) {  // rare exact fallback
    unsigned mask = 0;
#pragma unroll
    for (int r = 0; r < 16; ++r) {
      float vmin = 3.4e38f;
      int mmin = 0x7fffffff;
#pragma unroll
      for (int j = 0; j < 32; ++j) {
        bool ok = !((mask >> j) & 1u) && (d[j] < vmin);
        if (ok) { vmin = d[j]; mmin = j * 64 + lane; }
      }
#pragma unroll
      for (int s = 1; s < 64; s <<= 1) {
        float ov = __shfl_xor(vmin, s, 64);
        int om = __shfl_xor(mmin, s, 64);
        if (ov < vmin || (ov == vmin && om < mmin)) { vmin = ov; mmin = om; }
      }
      widx[r] = mmin;
      if (lane == (mmin & 63)) mask |= 1u << (mmin >> 6);
    }
  }
  float sx = 0, sy = 0, sz = 0;
#pragma unroll
  for (int r = 0; r < 16; ++r) {
    float4 v = xsq[widx[r]];
    sx += v.x; sy += v.y; sz += v.z;
  }
  const float mx = sx * 0.0625f, my = sy * 0.0625f, mz = sz * 0.0625f;
  float cxx = 0, cxy = 0, cxz = 0, cyy = 0, cyz = 0, czz = 0;
#pragma unroll
  for (int r = 0; r < 16; ++r) {
    float4 v = xsq[widx[r]];
    float ax = v.x - mx, ay = v.y - my, az = v.z - mz;
    cxx = fmaf(ax, ax, cxx); cxy = fmaf(ax, ay, cxy); cxz = fmaf(ax, az, cxz);
    cyy = fmaf(ay, ay, cyy); cyz = fmaf(ay, az, cyz); czz = fmaf(az, az, czz);
  }
  if (lane == 0) {
    float* o = h0 + ((size_t)b * NPTS + nq) * 12;
    *(float4*)&o[0] = make_float4(q4.x, q4.y, q4.z, cxx);
    *(float4*)&o[4] = make_float4(cxy, cxz, cxy, cyy);
    *(float4*)&o[8] = make_float4(cyz, cxz, cyz, czz);
  }
}

// ---------------------------------------------------------------- MLP1 (12->12->64->64, BN folded) + bf16 plane epilogue
__global__ __launch_bounds__(256) void k_mlp1(
    const float* __restrict__ h0,
    const float* __restrict__ w1, const float* __restrict__ cb1,
    const float* __restrict__ w2, const float* __restrict__ cb2,
    const float* __restrict__ w3, const float* __restrict__ cb3,
    const float* __restrict__ bn1g, const float* __restrict__ bn1b,
    const float* __restrict__ bn1m, const float* __restrict__ bn1v,
    const float* __restrict__ bn2g, const float* __restrict__ bn2b,
    const float* __restrict__ bn2m, const float* __restrict__ bn2v,
    const float* __restrict__ bn3g, const float* __restrict__ bn3b,
    const float* __restrict__ bn3m, const float* __restrict__ bn3v,
    float* __restrict__ h3out,
    unsigned short* __restrict__ h3hi, unsigned short* __restrict__ h3lo) {
  __shared__ float W1[144], W2[768], W3[4096];
  __shared__ float S1[12], F1[12], S2[64], F2[64], S3[64], F3[64];
  __shared__ float h0s[64][12];
  __shared__ float A2[64][65];
  const int tid = threadIdx.x;
  for (int i = tid; i < 144; i += 256) W1[i] = w1[i];
  for (int i = tid; i < 768; i += 256) W2[i] = w2[i];
  for (int i = tid; i < 4096; i += 256) W3[i] = w3[i];
  if (tid < 12) {
    float s = bn1g[tid] * rsqrtf(bn1v[tid] + 1e-3f);
    S1[tid] = s; F1[tid] = (cb1[tid] - bn1m[tid]) * s + bn1b[tid];
  }
  if (tid < 64) {
    float s2 = bn2g[tid] * rsqrtf(bn2v[tid] + 1e-3f);
    S2[tid] = s2; F2[tid] = (cb2[tid] - bn2m[tid]) * s2 + bn2b[tid];
    float s3 = bn3g[tid] * rsqrtf(bn3v[tid] + 1e-3f);
    S3[tid] = s3; F3[tid] = (cb3[tid] - bn3m[tid]) * s3 + bn3b[tid];
  }
  const int p0 = blockIdx.x * 64;
  for (int i = tid; i < 64 * 12; i += 256)
    h0s[i / 12][i % 12] = h0[(size_t)p0 * 12 + i];
  __syncthreads();
  const int pl = tid >> 2;
  const int q = tid & 3;
  float v1[12];
#pragma unroll
  for (int o = 0; o < 12; ++o) {
    float a = 0.f;
#pragma unroll
    for (int i = 0; i < 12; ++i) a = fmaf(h0s[pl][i], W1[i * 12 + o], a);
    v1[o] = fmaxf(fmaf(a, S1[o], F1[o]), 0.f);
  }
#pragma unroll
  for (int o = 0; o < 16; ++o) {
    int oo = q * 16 + o;
    float a = 0.f;
#pragma unroll
    for (int i = 0; i < 12; ++i) a = fmaf(v1[i], W2[i * 64 + oo], a);
    A2[pl][oo] = fmaxf(fmaf(a, S2[oo], F2[oo]), 0.f);
  }
  __syncthreads();
  float acc[16];
#pragma unroll
  for (int o = 0; o < 16; ++o) acc[o] = 0.f;
  for (int i = 0; i < 64; ++i) {
    float xv = A2[pl][i];
#pragma unroll
    for (int o = 0; o < 16; ++o) acc[o] = fmaf(xv, W3[i * 64 + q * 16 + o], acc[o]);
  }
  float vals[16];
#pragma unroll
  for (int o = 0; o < 16; ++o) {
    int oo = q * 16 + o;
    vals[o] = fmaxf(fmaf(acc[o], S3[oo], F3[oo]), 0.f);
  }
  const size_t rowo = (size_t)(p0 + pl) * 64 + q * 16;
  float* orow = h3out + rowo;
#pragma unroll
  for (int o4 = 0; o4 < 4; ++o4)
    *(float4*)&orow[4 * o4] = make_float4(vals[4 * o4], vals[4 * o4 + 1],
                                          vals[4 * o4 + 2], vals[4 * o4 + 3]);
  bf16x8 hv0, hv1, lv0, lv1;
#pragma unroll
  for (int o = 0; o < 8; ++o) {
    unsigned short hb = f2bf(vals[o]);
    hv0[o] = (short)hb; lv0[o] = (short)f2bf(vals[o] - bf2f(hb));
    unsigned short hb1 = f2bf(vals[8 + o]);
    hv1[o] = (short)hb1; lv1[o] = (short)f2bf(vals[8 + o] - bf2f(hb1));
  }
  *(bf16x8*)&h3hi[rowo] = hv0; *(bf16x8*)&h3hi[rowo + 8] = hv1;
  *(bf16x8*)&h3lo[rowo] = lv0; *(bf16x8*)&h3lo[rowo + 8] = lv1;
}

// ---------------------------------------------------------------- sq norms
template <int C>
__global__ __launch_bounds__(256) void k_sqnorm(const float* __restrict__ h,
                                                float* __restrict__ sq) {
  const int p = blockIdx.x * 256 + threadIdx.x;
  const float* row = h + (size_t)p * C;
  float a = 0.f;
#pragma unroll
  for (int i = 0; i < C; ++i) a = fmaf(row[i], row[i], a);
  sq[p] = a;
}

// ---------------------------------------------------------------- FUSED knn v5: 512 thr / 8 waves; 8 queries/block; 2 blocks/CU
// phase1: wave w computes 16q x 256cand (2 tiles), writes rows 0-7 -> dmat;
// phase2: wave w selects query w (R11 ballot-bisection, byte-identical).
#define DSTRIDE 2052
template <int C>
__global__ __launch_bounds__(512, 4) void k_knn_fused(
    const unsigned short* __restrict__ hi, const unsigned short* __restrict__ lo,
    const float* __restrict__ sq, const float* __restrict__ h,
    unsigned short* __restrict__ mhi, unsigned short* __restrict__ mlo) {
  __shared__ float dmat[8][DSTRIDE];   // ~65.7 KiB -> 2 blocks/CU
  __shared__ unsigned nidx[8][16];
  const int tid = threadIdx.x, lane = tid & 63, w = tid >> 6;
  // XCD swizzle: 4096 blocks, each XCD owns 2 batches
  const int f = blockIdx.x;
  const int g = ((f & 7) << 9) | (f >> 3);
  const int b = g >> 8;
  const int q0 = (g & 255) * 8;
  const size_t base = (size_t)b * NPTS * C;
  const float* __restrict__ sqb = sq + (size_t)b * NPTS;
  const int r = lane & 15, ks = (lane >> 4) * 8;
  const unsigned short* Ah = hi + base + (size_t)(q0 + r) * C + ks;
  const unsigned short* Al = lo + base + (size_t)(q0 + r) * C + ks;
  float sqq[4];
#pragma unroll
  for (int r2 = 0; r2 < 4; ++r2) sqq[r2] = sqb[q0 + (lane >> 4) * 4 + r2];

  // ---- phase 1: wave w -> candidates [w*256, w*256+256) as 2 tiles of 128
#pragma unroll 1
  for (int mt2 = 0; mt2 < 2; ++mt2) {
    const int m0 = w * 256 + mt2 * 128;
    const unsigned short* Bh = hi + base + (size_t)(m0 + r) * C + ks;
    const unsigned short* Bl = lo + base + (size_t)(m0 + r) * C + ks;
    f32x4 acc[8];
#pragma unroll
    for (int s = 0; s < 8; ++s) acc[s] = (f32x4){0.f, 0.f, 0.f, 0.f};
#pragma unroll
    for (int kk = 0; kk < C; kk += 32) {
      bf16x8 ah = *(const bf16x8*)(Ah + kk);
      bf16x8 al = *(const bf16x8*)(Al + kk);
#pragma unroll
      for (int s = 0; s < 8; ++s) {
        bf16x8 bh = *(const bf16x8*)(Bh + (size_t)s * 16 * C + kk);
        bf16x8 bl = *(const bf16x8*)(Bl + (size_t)s * 16 * C + kk);
        acc[s] = __builtin_amdgcn_mfma_f32_16x16x32_bf16(ah, bh, acc[s], 0, 0, 0);
        acc[s] = __builtin_amdgcn_mfma_f32_16x16x32_bf16(ah, bl, acc[s], 0, 0, 0);
        acc[s] = __builtin_amdgcn_mfma_f32_16x16x32_bf16(al, bh, acc[s], 0, 0, 0);
      }
    }
    if (lane < 32) {  // rows 0-7 only ((lane>>4)*4+r2 < 8)
#pragma unroll
      for (int s = 0; s < 8; ++s) {
        const int col = m0 + s * 16 + (lane & 15);
        float smc = sqb[col];
#pragma unroll
        for (int r2 = 0; r2 < 4; ++r2)
          dmat[(lane >> 4) * 4 + r2][col] = fmaf(-2.f, acc[s][r2], sqq[r2] + smc);
      }
    }
  }
  __syncthreads();

  // ---- phase 2: wave w selects query w (ballot-bisection)
  const float* __restrict__ hbp = h + base;
  const int q = q0 + w;
  uint64_t s0 = ~0ull, s1 = ~0ull, s2 = ~0ull, s3 = ~0ull;
#pragma unroll
  for (int t = 0; t < 8; ++t) {
    float4 dv = *(const float4*)&dmat[w][t * 256 + 4 * lane];
    const unsigned mb = (unsigned)(t * 256 + 4 * lane);
    pool_insert(((uint64_t)f2sort(dv.x) << 32) | (mb + 0), s0, s1, s2, s3);
    pool_insert(((uint64_t)f2sort(dv.y) << 32) | (mb + 1), s0, s1, s2, s3);
    pool_insert(((uint64_t)f2sort(dv.z) << 32) | (mb + 2), s0, s1, s2, s3);
    pool_insert(((uint64_t)f2sort(dv.w) << 32) | (mb + 3), s0, s1, s2, s3);
  }
  const unsigned h0 = (unsigned)(s0 >> 32), m0i = (unsigned)s0;
  const unsigned h1 = (unsigned)(s1 >> 32), m1i = (unsigned)s1;
  const unsigned h2 = (unsigned)(s2 >> 32), m2i = (unsigned)s2;
  const unsigned h3 = (unsigned)(s3 >> 32), m3i = (unsigned)s3;
  unsigned H = 0;
#pragma unroll 1
  for (int bit = 31; bit >= 0; --bit) {
    unsigned tr = H | (1u << bit);
    int c = __popcll(__ballot(h0 < tr)) + __popcll(__ballot(h1 < tr)) +
            __popcll(__ballot(h2 < tr)) + __popcll(__ballot(h3 < tr));
    if (c < 16) H = tr;
  }
  const int cs = __popcll(__ballot(h0 < H)) + __popcll(__ballot(h1 < H)) +
                 __popcll(__ballot(h2 < H)) + __popcll(__ballot(h3 < H));
  const int rneed = 16 - cs;
  const bool e0 = (h0 == H), e1 = (h1 == H), e2 = (h2 == H), e3 = (h3 == H);
  const int gsz = __popcll(__ballot(e0)) + __popcll(__ballot(e1)) +
                  __popcll(__ballot(e2)) + __popcll(__ballot(e3));
  unsigned I = 0xFFFFFFFFu;
  if (gsz > rneed) {
    unsigned Iv = 0;
#pragma unroll 1
    for (int bit = 10; bit >= 0; --bit) {
      unsigned tr = Iv | (1u << bit);
      int c2 = __popcll(__ballot(e0 && m0i < tr)) + __popcll(__ballot(e1 && m1i < tr)) +
               __popcll(__ballot(e2 && m2i < tr)) + __popcll(__ballot(e3 && m3i < tr));
      if (c2 < rneed) Iv = tr;
    }
    I = Iv;
  }
  const bool sel0 = (h0 < H) | (e0 & (m0i <= I));
  const bool sel1 = (h1 < H) | (e1 & (m1i <= I));
  const bool sel2 = (h2 < H) | (e2 & (m2i <= I));
  const bool sel3 = (h3 < H) | (e3 & (m3i <= I));
  const int nsel = (int)sel0 + sel1 + sel2 + sel3;
  float g0 = -3.4e38f, g1 = -3.4e38f;
  if (__ballot(nsel == 4) == 0ull) {
    unsigned long long bm;
    int bpos = 0;
    bm = __ballot(sel0); if (sel0) nidx[w][bpos + mbcnt64(bm)] = m0i; bpos += __popcll(bm);
    bm = __ballot(sel1); if (sel1) nidx[w][bpos + mbcnt64(bm)] = m1i; bpos += __popcll(bm);
    bm = __ballot(sel2); if (sel2) nidx[w][bpos + mbcnt64(bm)] = m2i; bpos += __popcll(bm);
    bm = __ballot(sel3); if (sel3) nidx[w][bpos + mbcnt64(bm)] = m3i;
#pragma unroll
    for (int rr = 0; rr < 16; ++rr) {
      unsigned m = nidx[w][rr];
      const float* row = hbp + (size_t)m * C;
      g0 = fmaxf(g0, row[lane]);
      if (C == 128) g1 = fmaxf(g1, row[64 + lane]);
    }
  } else {
    unsigned mask = 0u;
#pragma unroll 1
    for (int rr = 0; rr < 16; ++rr) {
      float vmin = 3.4e38f;
      int mmin = 0x7fffffff;
#pragma unroll
      for (int j = 0; j < 32; ++j) {
        const int m = (j >> 2) * 256 + 4 * lane + (j & 3);
        float dj = dmat[w][m];
        bool ok = !((mask >> j) & 1u) && (dj < vmin);
        if (ok) { vmin = dj; mmin = m; }
      }
#pragma unroll
      for (int s = 1; s < 64; s <<= 1) {
        float ov = __shfl_xor(vmin, s, 64);
        int om = __shfl_xor(mmin, s, 64);
        if (ov < vmin || (ov == vmin && om < mmin)) { vmin = ov; mmin = om; }
      }
      if (lane == ((mmin >> 2) & 63)) mask |= 1u << (((mmin >> 8) << 2) | (mmin & 3));
      const float* row = hbp + (size_t)mmin * C;
      g0 = fmaxf(g0, row[lane]);
      if (C == 128) g1 = fmaxf(g1, row[64 + lane]);
    }
  }
  const size_t orow = base + (size_t)q * C;
  unsigned short h0b = f2bf(g0);
  mhi[orow + lane] = h0b;
  mlo[orow + lane] = f2bf(g0 - bf2f(h0b));
  if (C == 128) {
    unsigned short h1b = f2bf(g1);
    mhi[orow + 64 + lane] = h1b;
    mlo[orow + 64 + lane] = f2bf(g1 - bf2f(h1b));
  }
}

// ---------------------------------------------------------------- combine denses -> W^T bf16 planes + bias
__global__ __launch_bounds__(256) void k_combine_t(const float* __restrict__ lw,
                                                   const float* __restrict__ lb,
                                                   const float* __restrict__ cw,
                                                   const float* __restrict__ cb,
                                                   unsigned short* __restrict__ wthi,
                                                   unsigned short* __restrict__ wtlo,
                                                   float* __restrict__ bc, int K, int M) {
  const int id = blockIdx.x * 256 + threadIdx.x;
  if (id < K * M) {
    int i = id / M, o = id % M;
    float a = 0.f;
    for (int k = 0; k < K; ++k) a = fmaf(lw[i * K + k], cw[k * M + o], a);
    unsigned short hb = f2bf(a);
    wthi[(size_t)o * K + i] = hb;
    wtlo[(size_t)o * K + i] = f2bf(a - bf2f(hb));
  }
  if (id < M) {
    float a = cb[id];
    for (int k = 0; k < K; ++k) a = fmaf(lb[k], cw[k * M + id], a);
    bc[id] = a;
  }
}

// ---------------------------------------------------------------- MFMA apply RELU (g1): 64 rows/block
template <int K, int M>
__global__ __launch_bounds__(256) void k_apply_relu(
    const unsigned short* __restrict__ Ah, const unsigned short* __restrict__ Al,
    const unsigned short* __restrict__ Wh, const unsigned short* __restrict__ Wl,
    const float* __restrict__ bias, float* __restrict__ fout,
    unsigned short* __restrict__ phi, unsigned short* __restrict__ plo) {
  const int tid = threadIdx.x, lane = tid & 63, w = tid >> 6;
  const int q0 = blockIdx.x * 64 + w * 16;
  const int m0 = blockIdx.y * 128;
  const int r = lane & 15, ks = (lane >> 4) * 8;
  const unsigned short* ap_h = Ah + (size_t)(q0 + r) * K + ks;
  const unsigned short* ap_l = Al + (size_t)(q0 + r) * K + ks;
  const unsigned short* bp_h = Wh + (size_t)(m0 + r) * K + ks;
  const unsigned short* bp_l = Wl + (size_t)(m0 + r) * K + ks;
  f32x4 acc[8];
#pragma unroll
  for (int mt = 0; mt < 8; ++mt) acc[mt] = (f32x4){0.f, 0.f, 0.f, 0.f};
#pragma unroll
  for (int kk = 0; kk < K; kk += 32) {
    bf16x8 ah = *(const bf16x8*)(ap_h + kk);
    bf16x8 al = *(const bf16x8*)(ap_l + kk);
#pragma unroll
    for (int mt = 0; mt < 8; ++mt) {
      bf16x8 bh = *(const bf16x8*)(bp_h + (size_t)mt * 16 * K + kk);
      bf16x8 bl = *(const bf16x8*)(bp_l + (size_t)mt * 16 * K + kk);
      acc[mt] = __builtin_amdgcn_mfma_f32_16x16x32_bf16(ah, bh, acc[mt], 0, 0, 0);
      acc[mt] = __builtin_amdgcn_mfma_f32_16x16x32_bf16(ah, bl, acc[mt], 0, 0, 0);
      acc[mt] = __builtin_amdgcn_mfma_f32_16x16x32_bf16(al, bh, acc[mt], 0, 0, 0);
    }
  }
#pragma unroll
  for (int mt = 0; mt < 8; ++mt) {
    const int col = m0 + mt * 16 + (lane & 15);
    const float bv = bias[col];
#pragma unroll
    for (int r2 = 0; r2 < 4; ++r2) {
      const int row = q0 + (lane >> 4) * 4 + r2;
      float v = fmaxf(acc[mt][r2] + bv, 0.f);
      const size_t idx = (size_t)row * M + col;
      fout[idx] = v;
      unsigned short hb = f2bf(v);
      phi[idx] = hb;
      plo[idx] = f2bf(v - bf2f(hb));
    }
  }
}

// ---------------------------------------------------------------- MFMA apply COLMAX (g2): 256 rows/block, W staged in LDS
#define WSTRIDE 136
__global__ __launch_bounds__(256, 2) void k_apply_colmax(
    const unsigned short* __restrict__ Ah, const unsigned short* __restrict__ Al,
    const unsigned short* __restrict__ Wh, const unsigned short* __restrict__ Wl,
    const float* __restrict__ bias, float* __restrict__ P) {
  constexpr int K = 128, M = 1024;
  __shared__ unsigned short Bh_s[128 * WSTRIDE];
  __shared__ unsigned short Bl_s[128 * WSTRIDE];
  __shared__ float cm[4][128];
  const int tid = threadIdx.x, lane = tid & 63, w = tid >> 6;
  const int rblk = blockIdx.x;
  const int m0 = blockIdx.y * 128;
  const int r = lane & 15, ks = (lane >> 4) * 8;
  for (int i = tid; i < 128 * 16; i += 256) {
    int row = i >> 4, c8 = (i & 15) * 8;
    *(bf16x8*)&Bh_s[row * WSTRIDE + c8] = *(const bf16x8*)&Wh[(size_t)(m0 + row) * K + c8];
    *(bf16x8*)&Bl_s[row * WSTRIDE + c8] = *(const bf16x8*)&Wl[(size_t)(m0 + row) * K + c8];
  }
  __syncthreads();
  const int q0 = rblk * 256 + w * 64;
  f32x4 acc[4][8];
#pragma unroll
  for (int st = 0; st < 4; ++st)
#pragma unroll
    for (int mt = 0; mt < 8; ++mt) acc[st][mt] = (f32x4){0.f, 0.f, 0.f, 0.f};
#pragma unroll
  for (int kk = 0; kk < K; kk += 32) {
    bf16x8 bh[8], bl[8];
#pragma unroll
    for (int mt = 0; mt < 8; ++mt) {
      bh[mt] = *(const bf16x8*)&Bh_s[(mt * 16 + r) * WSTRIDE + ks + kk];
      bl[mt] = *(const bf16x8*)&Bl_s[(mt * 16 + r) * WSTRIDE + ks + kk];
    }
#pragma unroll
    for (int st = 0; st < 4; ++st) {
      const unsigned short* ap_h = Ah + (size_t)(q0 + st * 16 + r) * K + ks + kk;
      const unsigned short* ap_l = Al + (size_t)(q0 + st * 16 + r) * K + ks + kk;
      bf16x8 ah = *(const bf16x8*)ap_h;
      bf16x8 al = *(const bf16x8*)ap_l;
#pragma unroll
      for (int mt = 0; mt < 8; ++mt) {
        acc[st][mt] = __builtin_amdgcn_mfma_f32_16x16x32_bf16(ah, bh[mt], acc[st][mt], 0, 0, 0);
        acc[st][mt] = __builtin_amdgcn_mfma_f32_16x16x32_bf16(ah, bl[mt], acc[st][mt], 0, 0, 0);
        acc[st][mt] = __builtin_amdgcn_mfma_f32_16x16x32_bf16(al, bh[mt], acc[st][mt], 0, 0, 0);
      }
    }
  }
#pragma unroll
  for (int mt = 0; mt < 8; ++mt) {
    float v = -3.4e38f;
#pragma unroll
    for (int st = 0; st < 4; ++st) {
      v = fmaxf(v, fmaxf(fmaxf(acc[st][mt][0], acc[st][mt][1]),
                         fmaxf(acc[st][mt][2], acc[st][mt][3])));
    }
    v = fmaxf(v, __shfl_xor(v, 16, 64));
    v = fmaxf(v, __shfl_xor(v, 32, 64));
    cm[w][mt * 16 + (lane & 15)] = v;
  }
  __syncthreads();
  if (tid < 128) {
    float m = fmaxf(fmaxf(cm[0][tid], cm[1][tid]), fmaxf(cm[2][tid], cm[3][tid]));
    P[(size_t)rblk * M + m0 + tid] = m + bias[m0 + tid];
  }
}

// ---------------------------------------------------------------- reduce P[128][1024] -> gmax[16][1024]
__global__ __launch_bounds__(256) void k_reduce_max(const float* __restrict__ P,
                                                    float* __restrict__ gmax) {
  const int b = blockIdx.x, tid = threadIdx.x;
  for (int c = tid; c < 1024; c += 256) {
    float m = P[(size_t)(b * 8) * 1024 + c];
    for (int rt = 1; rt < 8; ++rt)
      m = fmaxf(m, P[(size_t)(b * 8 + rt) * 1024 + c]);
    gmax[b * 1024 + c] = m;
  }
}

// ---------------------------------------------------------------- head part 1: hid = relu(gmax*W4+b4)
__global__ __launch_bounds__(256) void k_head1(const float* __restrict__ gmax,
                                               const float* __restrict__ w4,
                                               const float* __restrict__ b4,
                                               float* __restrict__ hid) {
  const int b = blockIdx.y, c0 = blockIdx.x * 64;
  const int tid = threadIdx.x;
  const int c = tid & 63, iq = tid >> 6;
  __shared__ float xs[1024];
  __shared__ float red[4][64];
  for (int i = tid; i < 1024; i += 256) xs[i] = gmax[b * 1024 + i];
  __syncthreads();
  float a = 0.f;
  for (int i = iq * 256; i < iq * 256 + 256; ++i)
    a = fmaf(xs[i], w4[(size_t)i * 1024 + c0 + c], a);
  red[iq][c] = a;
  __syncthreads();
  if (tid < 64) {
    float v = red[0][tid] + red[1][tid] + red[2][tid] + red[3][tid];
    hid[b * 1024 + c0 + tid] = fmaxf(v + b4[c0 + tid], 0.f);
  }
}

// ---------------------------------------------------------------- head part 2: out = hid*W5+b5
__global__ __launch_bounds__(256) void k_head2(const float* __restrict__ hid,
                                               const float* __restrict__ w5,
                                               const float* __restrict__ b5,
                                               float* __restrict__ out) {
  const int b = blockIdx.y, c0 = blockIdx.x * 64;
  const int tid = threadIdx.x;
  const int c = tid & 63, iq = tid >> 6;
  __shared__ float xs[1024];
  __shared__ float red[4][64];
  for (int i = tid; i < 1024; i += 256) xs[i] = hid[b * 1024 + i];
  __syncthreads();
  float a = 0.f;
  for (int i = iq * 256; i < iq * 256 + 256; ++i)
    a = fmaf(xs[i], w5[(size_t)i * 512 + c0 + c], a);
  red[iq][c] = a;
  __syncthreads();
  if (tid < 64) {
    float v = red[0][tid] + red[1][tid] + red[2][tid] + red[3][tid];
    out[(size_t)b * 512 + c0 + tid] = v + b5[c0 + tid];
  }
}

// ----------------------------------------------------------------
extern "C" void kernel_launch(void* const* d_in, const int* in_sizes, int n_in,
                              void* d_out, int out_size, void* d_ws, size_t ws_size,
                              hipStream_t stream) {
  (void)in_sizes; (void)n_in; (void)out_size; (void)ws_size;
  const float* x = (const float*)d_in[0];
  const float* w1 = (const float*)d_in[1];  const float* b1 = (const float*)d_in[2];
  const float* w2 = (const float*)d_in[3];  const float* b2 = (const float*)d_in[4];
  const float* w3 = (const float*)d_in[5];  const float* b3 = (const float*)d_in[6];
  const float* g1lw = (const float*)d_in[7];  const float* g1lb = (const float*)d_in[8];
  const float* g1cw = (const float*)d_in[9];  const float* g1cb = (const float*)d_in[10];
  const float* g2lw = (const float*)d_in[11]; const float* g2lb = (const float*)d_in[12];
  const float* g2cw = (const float*)d_in[13]; const float* g2cb = (const float*)d_in[14];
  const float* w4 = (const float*)d_in[15]; const float* b4 = (const float*)d_in[16];
  const float* w5 = (const float*)d_in[17]; const float* b5 = (const float*)d_in[18];
  const float* bn1g = (const float*)d_in[19]; const float* bn1b = (const float*)d_in[20];
  const float* bn1m = (const float*)d_in[21]; const float* bn1v = (const float*)d_in[22];
  const float* bn2g = (const float*)d_in[23]; const float* bn2b = (const float*)d_in[24];
  const float* bn2m = (const float*)d_in[25]; const float* bn2v = (const float*)d_in[26];
  const float* bn3g = (const float*)d_in[27]; const float* bn3b = (const float*)d_in[28];
  const float* bn3m = (const float*)d_in[29]; const float* bn3v = (const float*)d_in[30];

  float* ws = (float*)d_ws;
  size_t off = 0;
  auto alloc = [&](size_t n) { float* p = ws + off; off += (n + 63) & ~(size_t)63; return p; };
  float* slotA = alloc(16u * 2048 * 128);   // h0 then h4 f32
  float* slotB = alloc(16u * 2048 * 64);    // h3 f32
  float* sqv  = alloc(16u * 2048);
  unsigned short* hi_h = (unsigned short*)alloc(16u * 2048 * 64);
  unsigned short* lo_h = (unsigned short*)alloc(16u * 2048 * 64);
  unsigned short* mhi = (unsigned short*)alloc(16u * 2048 * 64);
  unsigned short* mlo = (unsigned short*)alloc(16u * 2048 * 64);
  unsigned short* wthi = (unsigned short*)alloc(65536);
  unsigned short* wtlo = (unsigned short*)alloc(65536);
  float* bc   = alloc(1024);
  float* P    = alloc(128u * 1024);
  float* gm   = alloc(16u * 1024);
  float* hid  = alloc(16u * 1024);

  // 1: knn on xyz + covariance -> h0[B,N,12]
  k_knn1_cov<<<dim3(512, 16), 256, 0, stream>>>(x, slotA);
  // 2: MLP1 -> h3 f32 + bf16 planes
  k_mlp1<<<512, 256, 0, stream>>>(slotA, w1, b1, w2, b2, w3, b3,
                                  bn1g, bn1b, bn1m, bn1v,
                                  bn2g, bn2b, bn2m, bn2v,
                                  bn3g, bn3b, bn3m, bn3v, slotB, hi_h, lo_h);
  // 3: knn(64) fused -> m1 planes
  k_sqnorm<64><<<128, 256, 0, stream>>>(slotB, sqv);
  k_knn_fused<64><<<4096, 512, 0, stream>>>(hi_h, lo_h, sqv, slotB, mhi, mlo);
  // 4: g1 combined dense 64->128 + relu -> h4 f32 + planes (MFMA)
  k_combine_t<<<32, 256, 0, stream>>>(g1lw, g1lb, g1cw, g1cb, wthi, wtlo, bc, 64, 128);
  k_apply_relu<64, 128><<<dim3(512, 1), 256, 0, stream>>>(
      mhi, mlo, wthi, wtlo, bc, slotA, hi_h, lo_h);
  // 5: knn(128) fused -> m2 planes
  k_sqnorm<128><<<128, 256, 0, stream>>>(slotA, sqv);
  k_knn_fused<128><<<4096, 512, 0, stream>>>(hi_h, lo_h, sqv, slotA, mhi, mlo);
  // 6: g2 combined dense 128->1024 + colmax -> P (MFMA, W in LDS, 256 rows/block)
  k_combine_t<<<512, 256, 0, stream>>>(g2lw, g2lb, g2cw, g2cb, wthi, wtlo, bc, 128, 1024);
  k_apply_colmax<<<dim3(128, 8), 256, 0, stream>>>(mhi, mlo, wthi, wtlo, bc, P);
  // 7: reduce -> gmax[16][1024]
  k_reduce_max<<<16, 256, 0, stream>>>(P, gm);
  // 8: head -> out[16][512]
  k_head1<<<dim3(16, 16), 256, 0, stream>>>(gm, w4, b4, hid);
  k_head2<<<dim3(8, 16), 256, 0, stream>>>(hid, w5, b5, (float*)d_out);
}

// Round 15
// 890.277 us; speedup vs baseline: 1.2894x; 1.2894x over previous
//
#include <hip/hip_runtime.h>
#include <cstddef>
#include <cstdint>

#define NPTS 2048

typedef short bf16x8 __attribute__((ext_vector_type(8)));
typedef float f32x4 __attribute__((ext_vector_type(4)));

__device__ __forceinline__ unsigned short f2bf(float f) {
  unsigned u = __builtin_bit_cast(unsigned, f);
  unsigned r = u + 0x7fffu + ((u >> 16) & 1u);  // RNE (finite inputs)
  return (unsigned short)(r >> 16);
}
__device__ __forceinline__ float bf2f(unsigned short s) {
  unsigned u = ((unsigned)s) << 16;
  return __builtin_bit_cast(float, u);
}
// float -> order-preserving u32 (handles negatives)
__device__ __forceinline__ unsigned f2sort(float f) {
  unsigned u = __builtin_bit_cast(unsigned, f);
  return u ^ (unsigned)(((int)u >> 31) | 0x80000000);
}

// sorted-4 pool insert (ascending); keys unique
__device__ __forceinline__ void pool_insert(uint64_t k, uint64_t& s0, uint64_t& s1,
                                            uint64_t& s2, uint64_t& s3) {
  s3 = k < s3 ? k : s3;
  uint64_t t;
  t = s2 < s3 ? s2 : s3; s3 = s2 < s3 ? s3 : s2; s2 = t;
  t = s1 < s2 ? s1 : s2; s2 = s1 < s2 ? s2 : s1; s1 = t;
  t = s0 < s1 ? s0 : s1; s1 = s0 < s1 ? s1 : s0; s0 = t;
}

__device__ __forceinline__ int mbcnt64(unsigned long long m) {
  return __builtin_amdgcn_mbcnt_hi((unsigned)(m >> 32),
                                   __builtin_amdgcn_mbcnt_lo((unsigned)m, 0));
}

__device__ __forceinline__ float wave_sum_f32(float v) {
#pragma unroll
  for (int s = 1; s < 64; s <<= 1) v += __shfl_xor(v, s, 64);
  return v;
}

// ---------------------------------------------------------------- knn1 + cov (1 query per wave, ballot-bisection select)
__global__ __launch_bounds__(256) void k_knn1_cov(const float* __restrict__ x,
                                                  float* __restrict__ h0) {
  const int b = blockIdx.y;
  const int tid = threadIdx.x;
  const int lane = tid & 63;
  const int w = tid >> 6;
  __shared__ float4 xsq[NPTS];
  const float* xb = x + (size_t)b * NPTS * 3;
  for (int i = tid; i < NPTS; i += 256) {
    float a0 = xb[3 * i], a1 = xb[3 * i + 1], a2 = xb[3 * i + 2];
    xsq[i] = make_float4(a0, a1, a2, fmaf(a0, a0, fmaf(a1, a1, a2 * a2)));
  }
  __syncthreads();
  const int nq = blockIdx.x * 4 + w;
  const float4 q4 = xsq[nq];
  const float sqq = q4.w;
  float d[32];
  uint64_t s0 = ~0ull, s1 = ~0ull, s2 = ~0ull, s3 = ~0ull;
#pragma unroll
  for (int j = 0; j < 32; ++j) {
    float4 v = xsq[j * 64 + lane];
    float dot = q4.x * v.x;
    dot = fmaf(q4.y, v.y, dot);
    dot = fmaf(q4.z, v.z, dot);
    float dd = fmaf(-2.f, dot, sqq + v.w);
    d[j] = dd;
    uint64_t k = ((uint64_t)f2sort(dd) << 32) | (unsigned)(j * 64 + lane);
    pool_insert(k, s0, s1, s2, s3);
  }
  const unsigned h0w = (unsigned)(s0 >> 32), m0i = (unsigned)s0;
  const unsigned h1w = (unsigned)(s1 >> 32), m1i = (unsigned)s1;
  const unsigned h2w = (unsigned)(s2 >> 32), m2i = (unsigned)s2;
  const unsigned h3w = (unsigned)(s3 >> 32), m3i = (unsigned)s3;
  unsigned H = 0;
#pragma unroll 1
  for (int bit = 31; bit >= 0; --bit) {
    unsigned tr = H | (1u << bit);
    int c = __popcll(__ballot(h0w < tr)) + __popcll(__ballot(h1w < tr)) +
            __popcll(__ballot(h2w < tr)) + __popcll(__ballot(h3w < tr));
    if (c < 16) H = tr;
  }
  const int cs = __popcll(__ballot(h0w < H)) + __popcll(__ballot(h1w < H)) +
                 __popcll(__ballot(h2w < H)) + __popcll(__ballot(h3w < H));
  const int rneed = 16 - cs;
  const bool e0 = (h0w == H), e1 = (h1w == H), e2 = (h2w == H), e3 = (h3w == H);
  const int gsz = __popcll(__ballot(e0)) + __popcll(__ballot(e1)) +
                  __popcll(__ballot(e2)) + __popcll(__ballot(e3));
  unsigned I = 0xFFFFFFFFu;
  if (gsz > rneed) {  // rare: resolve boundary ties by index bisection (11 bits)
    unsigned Iv = 0;
#pragma unroll 1
    for (int bit = 10; bit >= 0; --bit) {
      unsigned tr = Iv | (1u << bit);
      int c2 = __popcll(__ballot(e0 && m0i < tr)) + __popcll(__ballot(e1 && m1i < tr)) +
               __popcll(__ballot(e2 && m2i < tr)) + __popcll(__ballot(e3 && m3i < tr));
      if (c2 < rneed) Iv = tr;
    }
    I = Iv;
  }
  const bool sel0 = (h0w < H) | (e0 & (m0i <= I));
  const bool sel1 = (h1w < H) | (e1 & (m1i <= I));
  const bool sel2 = (h2w < H) | (e2 & (m2i <= I));
  const bool sel3 = (h3w < H) | (e3 & (m3i <= I));
  const int nsel = (int)sel0 + sel1 + sel2 + sel3;
  float cxx, cxy, cxz, cyy, cyz, czz;
  if (__ballot(nsel == 4) == 0ull) {  // normal: selected set == exact top-16
    float4 z = make_float4(0.f, 0.f, 0.f, 0.f);
    float4 v0 = sel0 ? xsq[m0i] : z;
    float4 v1 = sel1 ? xsq[m1i] : z;
    float4 v2 = sel2 ? xsq[m2i] : z;
    float4 v3 = sel3 ? xsq[m3i] : z;
    float sx = wave_sum_f32(v0.x + v1.x + v2.x + v3.x);
    float sy = wave_sum_f32(v0.y + v1.y + v2.y + v3.y);
    float sz = wave_sum_f32(v0.z + v1.z + v2.z + v3.z);
    const float mx = sx * 0.0625f, my = sy * 0.0625f, mz = sz * 0.0625f;
    float w0 = sel0 ? 1.f : 0.f, w1 = sel1 ? 1.f : 0.f;
    float w2 = sel2 ? 1.f : 0.f, w3 = sel3 ? 1.f : 0.f;
    float a0x = v0.x - mx, a0y = v0.y - my, a0z = v0.z - mz;
    float a1x = v1.x - mx, a1y = v1.y - my, a1z = v1.z - mz;
    float a2x = v2.x - mx, a2y = v2.y - my, a2z = v2.z - mz;
    float a3x = v3.x - mx, a3y = v3.y - my, a3z = v3.z - mz;
    float pxx = (w0 * a0x) * a0x + (w1 * a1x) * a1x + (w2 * a2x) * a2x + (w3 * a3x) * a3x;
    float pxy = (w0 * a0x) * a0y + (w1 * a1x) * a1y + (w2 * a2x) * a2y + (w3 * a3x) * a3y;
    float pxz = (w0 * a0x) * a0z + (w1 * a1x) * a1z + (w2 * a2x) * a2z + (w3 * a3x) * a3z;
    float pyy = (w0 * a0y) * a0y + (w1 * a1y) * a1y + (w2 * a2y) * a2y + (w3 * a3y) * a3y;
    float pyz = (w0 * a0y) * a0z + (w1 * a1y) * a1z + (w2 * a2y) * a2z + (w3 * a3y) * a3z;
    float pzz = (w0 * a0z) * a0z + (w1 * a1z) * a1z + (w2 * a2z) * a2z + (w3 * a3z) * a3z;
    cxx = wave_sum_f32(pxx); cxy = wave_sum_f32(pxy); cxz = wave_sum_f32(pxz);
    cyy = wave_sum_f32(pyy); cyz = wave_sum_f32(pyz); czz = wave_sum_f32(pzz);
  } else {  // rare exact fallback: old masked rescan + serial mean/cov
    unsigned mask = 0;
    int widx[16];
#pragma unroll 1
    for (int r = 0; r < 16; ++r) {
      float vmin = 3.4e38f;
      int mmin = 0x7fffffff;
#pragma unroll
      for (int j = 0; j < 32; ++j) {
        bool ok = !((mask >> j) & 1u) && (d[j] < vmin);
        if (ok) { vmin = d[j]; mmin = j * 64 + lane; }
      }
#pragma unroll
      for (int s = 1; s < 64; s <<= 1) {
        float ov = __shfl_xor(vmin, s, 64);
        int om = __shfl_xor(mmin, s, 64);
        if (ov < vmin || (ov == vmin && om < mmin)) { vmin = ov; mmin = om; }
      }
      widx[r] = mmin;
      if (lane == (mmin & 63)) mask |= 1u << (mmin >> 6);
    }
    float sx = 0, sy = 0, sz = 0;
#pragma unroll
    for (int r = 0; r < 16; ++r) {
      float4 v = xsq[widx[r]];
      sx += v.x; sy += v.y; sz += v.z;
    }
    const float mx = sx * 0.0625f, my = sy * 0.0625f, mz = sz * 0.0625f;
    cxx = cxy = cxz = cyy = cyz = czz = 0.f;
#pragma unroll
    for (int r = 0; r < 16; ++r) {
      float4 v = xsq[widx[r]];
      float ax = v.x - mx, ay = v.y - my, az = v.z - mz;
      cxx = fmaf(ax, ax, cxx); cxy = fmaf(ax, ay, cxy); cxz = fmaf(ax, az, cxz);
      cyy = fmaf(ay, ay, cyy); cyz = fmaf(ay, az, cyz); czz = fmaf(az, az, czz);
    }
  }
  if (lane == 0) {
    float* o = h0 + ((size_t)b * NPTS + nq) * 12;
    *(float4*)&o[0] = make_float4(q4.x, q4.y, q4.z, cxx);
    *(float4*)&o[4] = make_float4(cxy, cxz, cxy, cyy);
    *(float4*)&o[8] = make_float4(cyz, cxz, cyz, czz);
  }
}

// ---------------------------------------------------------------- MLP1 (12->12->64->64, BN folded) + bf16 plane epilogue
__global__ __launch_bounds__(256) void k_mlp1(
    const float* __restrict__ h0,
    const float* __restrict__ w1, const float* __restrict__ cb1,
    const float* __restrict__ w2, const float* __restrict__ cb2,
    const float* __restrict__ w3, const float* __restrict__ cb3,
    const float* __restrict__ bn1g, const float* __restrict__ bn1b,
    const float* __restrict__ bn1m, const float* __restrict__ bn1v,
    const float* __restrict__ bn2g, const float* __restrict__ bn2b,
    const float* __restrict__ bn2m, const float* __restrict__ bn2v,
    const float* __restrict__ bn3g, const float* __restrict__ bn3b,
    const float* __restrict__ bn3m, const float* __restrict__ bn3v,
    float* __restrict__ h3out,
    unsigned short* __restrict__ h3hi, unsigned short* __restrict__ h3lo) {
  __shared__ float W1[144], W2[768], W3[4096];
  __shared__ float S1[12], F1[12], S2[64], F2[64], S3[64], F3[64];
  __shared__ float h0s[64][12];
  __shared__ float A2[64][65];
  const int tid = threadIdx.x;
  for (int i = tid; i < 144; i += 256) W1[i] = w1[i];
  for (int i = tid; i < 768; i += 256) W2[i] = w2[i];
  for (int i = tid; i < 4096; i += 256) W3[i] = w3[i];
  if (tid < 12) {
    float s = bn1g[tid] * rsqrtf(bn1v[tid] + 1e-3f);
    S1[tid] = s; F1[tid] = (cb1[tid] - bn1m[tid]) * s + bn1b[tid];
  }
  if (tid < 64) {
    float s2 = bn2g[tid] * rsqrtf(bn2v[tid] + 1e-3f);
    S2[tid] = s2; F2[tid] = (cb2[tid] - bn2m[tid]) * s2 + bn2b[tid];
    float s3 = bn3g[tid] * rsqrtf(bn3v[tid] + 1e-3f);
    S3[tid] = s3; F3[tid] = (cb3[tid] - bn3m[tid]) * s3 + bn3b[tid];
  }
  const int p0 = blockIdx.x * 64;
  for (int i = tid; i < 64 * 12; i += 256)
    h0s[i / 12][i % 12] = h0[(size_t)p0 * 12 + i];
  __syncthreads();
  const int pl = tid >> 2;
  const int q = tid & 3;
  float v1[12];
#pragma unroll
  for (int o = 0; o < 12; ++o) {
    float a = 0.f;
#pragma unroll
    for (int i = 0; i < 12; ++i) a = fmaf(h0s[pl][i], W1[i * 12 + o], a);
    v1[o] = fmaxf(fmaf(a, S1[o], F1[o]), 0.f);
  }
#pragma unroll
  for (int o = 0; o < 16; ++o) {
    int oo = q * 16 + o;
    float a = 0.f;
#pragma unroll
    for (int i = 0; i < 12; ++i) a = fmaf(v1[i], W2[i * 64 + oo], a);
    A2[pl][oo] = fmaxf(fmaf(a, S2[oo], F2[oo]), 0.f);
  }
  __syncthreads();
  float acc[16];
#pragma unroll
  for (int o = 0; o < 16; ++o) acc[o] = 0.f;
  for (int i = 0; i < 64; ++i) {
    float xv = A2[pl][i];
#pragma unroll
    for (int o = 0; o < 16; ++o) acc[o] = fmaf(xv, W3[i * 64 + q * 16 + o], acc[o]);
  }
  float vals[16];
#pragma unroll
  for (int o = 0; o < 16; ++o) {
    int oo = q * 16 + o;
    vals[o] = fmaxf(fmaf(acc[o], S3[oo], F3[oo]), 0.f);
  }
  const size_t rowo = (size_t)(p0 + pl) * 64 + q * 16;
  float* orow = h3out + rowo;
#pragma unroll
  for (int o4 = 0; o4 < 4; ++o4)
    *(float4*)&orow[4 * o4] = make_float4(vals[4 * o4], vals[4 * o4 + 1],
                                          vals[4 * o4 + 2], vals[4 * o4 + 3]);
  bf16x8 hv0, hv1, lv0, lv1;
#pragma unroll
  for (int o = 0; o < 8; ++o) {
    unsigned short hb = f2bf(vals[o]);
    hv0[o] = (short)hb; lv0[o] = (short)f2bf(vals[o] - bf2f(hb));
    unsigned short hb1 = f2bf(vals[8 + o]);
    hv1[o] = (short)hb1; lv1[o] = (short)f2bf(vals[8 + o] - bf2f(hb1));
  }
  *(bf16x8*)&h3hi[rowo] = hv0; *(bf16x8*)&h3hi[rowo + 8] = hv1;
  *(bf16x8*)&h3lo[rowo] = lv0; *(bf16x8*)&h3lo[rowo + 8] = lv1;
}

// ---------------------------------------------------------------- sq norms
template <int C>
__global__ __launch_bounds__(256) void k_sqnorm(const float* __restrict__ h,
                                                float* __restrict__ sq) {
  const int p = blockIdx.x * 256 + threadIdx.x;
  const float* row = h + (size_t)p * C;
  float a = 0.f;
#pragma unroll
  for (int i = 0; i < C; ++i) a = fmaf(row[i], row[i], a);
  sq[p] = a;
}

// ---------------------------------------------------------------- FUSED knn v4 (R13-proven): MFMA dist -> LDS -> ballot-bisection select
#define DSTRIDE 2052
template <int C>
__global__ __launch_bounds__(1024, 4) void k_knn_fused(
    const unsigned short* __restrict__ hi, const unsigned short* __restrict__ lo,
    const float* __restrict__ sq, const float* __restrict__ h,
    unsigned short* __restrict__ mhi, unsigned short* __restrict__ mlo) {
  __shared__ float dmat[16][DSTRIDE];
  __shared__ unsigned nidx[16][16];
  const int tid = threadIdx.x, lane = tid & 63, w = tid >> 6;
  const int f = blockIdx.x;
  const int g = ((f & 7) << 8) | (f >> 3);
  const int b = g >> 7;
  const int q0 = (g & 127) * 16;
  const size_t base = (size_t)b * NPTS * C;
  const float* __restrict__ sqb = sq + (size_t)b * NPTS;
  const int r = lane & 15, ks = (lane >> 4) * 8;
  const unsigned short* Ah = hi + base + (size_t)(q0 + r) * C + ks;
  const unsigned short* Al = lo + base + (size_t)(q0 + r) * C + ks;
  float sqq[4];
#pragma unroll
  for (int r2 = 0; r2 < 4; ++r2) sqq[r2] = sqb[q0 + (lane >> 4) * 4 + r2];

  // ---- phase 1: wave w -> candidates [w*128, w*128+128)
  {
    const int m0 = w * 128;
    const unsigned short* Bh = hi + base + (size_t)(m0 + r) * C + ks;
    const unsigned short* Bl = lo + base + (size_t)(m0 + r) * C + ks;
    f32x4 acc[8];
#pragma unroll
    for (int s = 0; s < 8; ++s) acc[s] = (f32x4){0.f, 0.f, 0.f, 0.f};
#pragma unroll
    for (int kk = 0; kk < C; kk += 32) {
      bf16x8 ah = *(const bf16x8*)(Ah + kk);
      bf16x8 al = *(const bf16x8*)(Al + kk);
#pragma unroll
      for (int s = 0; s < 8; ++s) {
        bf16x8 bh = *(const bf16x8*)(Bh + (size_t)s * 16 * C + kk);
        bf16x8 bl = *(const bf16x8*)(Bl + (size_t)s * 16 * C + kk);
        acc[s] = __builtin_amdgcn_mfma_f32_16x16x32_bf16(ah, bh, acc[s], 0, 0, 0);
        acc[s] = __builtin_amdgcn_mfma_f32_16x16x32_bf16(ah, bl, acc[s], 0, 0, 0);
        acc[s] = __builtin_amdgcn_mfma_f32_16x16x32_bf16(al, bh, acc[s], 0, 0, 0);
      }
    }
#pragma unroll
    for (int s = 0; s < 8; ++s) {
      const int col = m0 + s * 16 + (lane & 15);
      float smc = sqb[col];
#pragma unroll
      for (int r2 = 0; r2 < 4; ++r2)
        dmat[(lane >> 4) * 4 + r2][col] = fmaf(-2.f, acc[s][r2], sqq[r2] + smc);
    }
  }
  __syncthreads();

  // ---- phase 2: wave w selects query w (ballot-bisection)
  const float* __restrict__ hbp = h + base;
  const int q = q0 + w;
  uint64_t s0 = ~0ull, s1 = ~0ull, s2 = ~0ull, s3 = ~0ull;
#pragma unroll
  for (int t = 0; t < 8; ++t) {
    float4 dv = *(const float4*)&dmat[w][t * 256 + 4 * lane];
    const unsigned mb = (unsigned)(t * 256 + 4 * lane);
    pool_insert(((uint64_t)f2sort(dv.x) << 32) | (mb + 0), s0, s1, s2, s3);
    pool_insert(((uint64_t)f2sort(dv.y) << 32) | (mb + 1), s0, s1, s2, s3);
    pool_insert(((uint64_t)f2sort(dv.z) << 32) | (mb + 2), s0, s1, s2, s3);
    pool_insert(((uint64_t)f2sort(dv.w) << 32) | (mb + 3), s0, s1, s2, s3);
  }
  const unsigned h0 = (unsigned)(s0 >> 32), m0i = (unsigned)s0;
  const unsigned h1 = (unsigned)(s1 >> 32), m1i = (unsigned)s1;
  const unsigned h2 = (unsigned)(s2 >> 32), m2i = (unsigned)s2;
  const unsigned h3 = (unsigned)(s3 >> 32), m3i = (unsigned)s3;
  unsigned H = 0;
#pragma unroll 1
  for (int bit = 31; bit >= 0; --bit) {
    unsigned tr = H | (1u << bit);
    int c = __popcll(__ballot(h0 < tr)) + __popcll(__ballot(h1 < tr)) +
            __popcll(__ballot(h2 < tr)) + __popcll(__ballot(h3 < tr));
    if (c < 16) H = tr;
  }
  const int cs = __popcll(__ballot(h0 < H)) + __popcll(__ballot(h1 < H)) +
                 __popcll(__ballot(h2 < H)) + __popcll(__ballot(h3 < H));
  const int rneed = 16 - cs;
  const bool e0 = (h0 == H), e1 = (h1 == H), e2 = (h2 == H), e3 = (h3 == H);
  const int gsz = __popcll(__ballot(e0)) + __popcll(__ballot(e1)) +
                  __popcll(__ballot(e2)) + __popcll(__ballot(e3));
  unsigned I = 0xFFFFFFFFu;
  if (gsz > rneed) {
    unsigned Iv = 0;
#pragma unroll 1
    for (int bit = 10; bit >= 0; --bit) {
      unsigned tr = Iv | (1u << bit);
      int c2 = __popcll(__ballot(e0 && m0i < tr)) + __popcll(__ballot(e1 && m1i < tr)) +
               __popcll(__ballot(e2 && m2i < tr)) + __popcll(__ballot(e3 && m3i < tr));
      if (c2 < rneed) Iv = tr;
    }
    I = Iv;
  }
  const bool sel0 = (h0 < H) | (e0 & (m0i <= I));
  const bool sel1 = (h1 < H) | (e1 & (m1i <= I));
  const bool sel2 = (h2 < H) | (e2 & (m2i <= I));
  const bool sel3 = (h3 < H) | (e3 & (m3i <= I));
  const int nsel = (int)sel0 + sel1 + sel2 + sel3;
  float g0 = -3.4e38f, g1 = -3.4e38f;
  if (__ballot(nsel == 4) == 0ull) {
    unsigned long long bm;
    int bpos = 0;
    bm = __ballot(sel0); if (sel0) nidx[w][bpos + mbcnt64(bm)] = m0i; bpos += __popcll(bm);
    bm = __ballot(sel1); if (sel1) nidx[w][bpos + mbcnt64(bm)] = m1i; bpos += __popcll(bm);
    bm = __ballot(sel2); if (sel2) nidx[w][bpos + mbcnt64(bm)] = m2i; bpos += __popcll(bm);
    bm = __ballot(sel3); if (sel3) nidx[w][bpos + mbcnt64(bm)] = m3i;
#pragma unroll
    for (int rr = 0; rr < 16; ++rr) {
      unsigned m = nidx[w][rr];
      const float* row = hbp + (size_t)m * C;
      g0 = fmaxf(g0, row[lane]);
      if (C == 128) g1 = fmaxf(g1, row[64 + lane]);
    }
  } else {
    unsigned mask = 0u;
#pragma unroll 1
    for (int rr = 0; rr < 16; ++rr) {
      float vmin = 3.4e38f;
      int mmin = 0x7fffffff;
#pragma unroll
      for (int j = 0; j < 32; ++j) {
        const int m = (j >> 2) * 256 + 4 * lane + (j & 3);
        float dj = dmat[w][m];
        bool ok = !((mask >> j) & 1u) && (dj < vmin);
        if (ok) { vmin = dj; mmin = m; }
      }
#pragma unroll
      for (int s = 1; s < 64; s <<= 1) {
        float ov = __shfl_xor(vmin, s, 64);
        int om = __shfl_xor(mmin, s, 64);
        if (ov < vmin || (ov == vmin && om < mmin)) { vmin = ov; mmin = om; }
      }
      if (lane == ((mmin >> 2) & 63)) mask |= 1u << (((mmin >> 8) << 2) | (mmin & 3));
      const float* row = hbp + (size_t)mmin * C;
      g0 = fmaxf(g0, row[lane]);
      if (C == 128) g1 = fmaxf(g1, row[64 + lane]);
    }
  }
  const size_t orow = base + (size_t)q * C;
  unsigned short h0b = f2bf(g0);
  mhi[orow + lane] = h0b;
  mlo[orow + lane] = f2bf(g0 - bf2f(h0b));
  if (C == 128) {
    unsigned short h1b = f2bf(g1);
    mhi[orow + 64 + lane] = h1b;
    mlo[orow + 64 + lane] = f2bf(g1 - bf2f(h1b));
  }
}

// ---------------------------------------------------------------- combine denses -> W^T bf16 planes + bias
__global__ __launch_bounds__(256) void k_combine_t(const float* __restrict__ lw,
                                                   const float* __restrict__ lb,
                                                   const float* __restrict__ cw,
                                                   const float* __restrict__ cb,
                                                   unsigned short* __restrict__ wthi,
                                                   unsigned short* __restrict__ wtlo,
                                                   float* __restrict__ bc, int K, int M) {
  const int id = blockIdx.x * 256 + threadIdx.x;
  if (id < K * M) {
    int i = id / M, o = id % M;
    float a = 0.f;
    for (int k = 0; k < K; ++k) a = fmaf(lw[i * K + k], cw[k * M + o], a);
    unsigned short hb = f2bf(a);
    wthi[(size_t)o * K + i] = hb;
    wtlo[(size_t)o * K + i] = f2bf(a - bf2f(hb));
  }
  if (id < M) {
    float a = cb[id];
    for (int k = 0; k < K; ++k) a = fmaf(lb[k], cw[k * M + id], a);
    bc[id] = a;
  }
}

// ---------------------------------------------------------------- MFMA apply RELU (g1): 64 rows/block
template <int K, int M>
__global__ __launch_bounds__(256) void k_apply_relu(
    const unsigned short* __restrict__ Ah, const unsigned short* __restrict__ Al,
    const unsigned short* __restrict__ Wh, const unsigned short* __restrict__ Wl,
    const float* __restrict__ bias, float* __restrict__ fout,
    unsigned short* __restrict__ phi, unsigned short* __restrict__ plo) {
  const int tid = threadIdx.x, lane = tid & 63, w = tid >> 6;
  const int q0 = blockIdx.x * 64 + w * 16;
  const int m0 = blockIdx.y * 128;
  const int r = lane & 15, ks = (lane >> 4) * 8;
  const unsigned short* ap_h = Ah + (size_t)(q0 + r) * K + ks;
  const unsigned short* ap_l = Al + (size_t)(q0 + r) * K + ks;
  const unsigned short* bp_h = Wh + (size_t)(m0 + r) * K + ks;
  const unsigned short* bp_l = Wl + (size_t)(m0 + r) * K + ks;
  f32x4 acc[8];
#pragma unroll
  for (int mt = 0; mt < 8; ++mt) acc[mt] = (f32x4){0.f, 0.f, 0.f, 0.f};
#pragma unroll
  for (int kk = 0; kk < K; kk += 32) {
    bf16x8 ah = *(const bf16x8*)(ap_h + kk);
    bf16x8 al = *(const bf16x8*)(ap_l + kk);
#pragma unroll
    for (int mt = 0; mt < 8; ++mt) {
      bf16x8 bh = *(const bf16x8*)(bp_h + (size_t)mt * 16 * K + kk);
      bf16x8 bl = *(const bf16x8*)(bp_l + (size_t)mt * 16 * K + kk);
      acc[mt] = __builtin_amdgcn_mfma_f32_16x16x32_bf16(ah, bh, acc[mt], 0, 0, 0);
      acc[mt] = __builtin_amdgcn_mfma_f32_16x16x32_bf16(ah, bl, acc[mt], 0, 0, 0);
      acc[mt] = __builtin_amdgcn_mfma_f32_16x16x32_bf16(al, bh, acc[mt], 0, 0, 0);
    }
  }
#pragma unroll
  for (int mt = 0; mt < 8; ++mt) {
    const int col = m0 + mt * 16 + (lane & 15);
    const float bv = bias[col];
#pragma unroll
    for (int r2 = 0; r2 < 4; ++r2) {
      const int row = q0 + (lane >> 4) * 4 + r2;
      float v = fmaxf(acc[mt][r2] + bv, 0.f);
      const size_t idx = (size_t)row * M + col;
      fout[idx] = v;
      unsigned short hb = f2bf(v);
      phi[idx] = hb;
      plo[idx] = f2bf(v - bf2f(hb));
    }
  }
}

// ---------------------------------------------------------------- MFMA apply COLMAX (g2): 256 rows/block, W staged in LDS
#define WSTRIDE 136
__global__ __launch_bounds__(256, 2) void k_apply_colmax(
    const unsigned short* __restrict__ Ah, const unsigned short* __restrict__ Al,
    const unsigned short* __restrict__ Wh, const unsigned short* __restrict__ Wl,
    const float* __restrict__ bias, float* __restrict__ P) {
  constexpr int K = 128, M = 1024;
  __shared__ unsigned short Bh_s[128 * WSTRIDE];
  __shared__ unsigned short Bl_s[128 * WSTRIDE];
  __shared__ float cm[4][128];
  const int tid = threadIdx.x, lane = tid & 63, w = tid >> 6;
  const int rblk = blockIdx.x;
  const int m0 = blockIdx.y * 128;
  const int r = lane & 15, ks = (lane >> 4) * 8;
  for (int i = tid; i < 128 * 16; i += 256) {
    int row = i >> 4, c8 = (i & 15) * 8;
    *(bf16x8*)&Bh_s[row * WSTRIDE + c8] = *(const bf16x8*)&Wh[(size_t)(m0 + row) * K + c8];
    *(bf16x8*)&Bl_s[row * WSTRIDE + c8] = *(const bf16x8*)&Wl[(size_t)(m0 + row) * K + c8];
  }
  __syncthreads();
  const int q0 = rblk * 256 + w * 64;
  f32x4 acc[4][8];
#pragma unroll
  for (int st = 0; st < 4; ++st)
#pragma unroll
    for (int mt = 0; mt < 8; ++mt) acc[st][mt] = (f32x4){0.f, 0.f, 0.f, 0.f};
#pragma unroll
  for (int kk = 0; kk < K; kk += 32) {
    bf16x8 bh[8], bl[8];
#pragma unroll
    for (int mt = 0; mt < 8; ++mt) {
      bh[mt] = *(const bf16x8*)&Bh_s[(mt * 16 + r) * WSTRIDE + ks + kk];
      bl[mt] = *(const bf16x8*)&Bl_s[(mt * 16 + r) * WSTRIDE + ks + kk];
    }
#pragma unroll
    for (int st = 0; st < 4; ++st) {
      const unsigned short* ap_h = Ah + (size_t)(q0 + st * 16 + r) * K + ks + kk;
      const unsigned short* ap_l = Al + (size_t)(q0 + st * 16 + r) * K + ks + kk;
      bf16x8 ah = *(const bf16x8*)ap_h;
      bf16x8 al = *(const bf16x8*)ap_l;
#pragma unroll
      for (int mt = 0; mt < 8; ++mt) {
        acc[st][mt] = __builtin_amdgcn_mfma_f32_16x16x32_bf16(ah, bh[mt], acc[st][mt], 0, 0, 0);
        acc[st][mt] = __builtin_amdgcn_mfma_f32_16x16x32_bf16(ah, bl[mt], acc[st][mt], 0, 0, 0);
        acc[st][mt] = __builtin_amdgcn_mfma_f32_16x16x32_bf16(al, bh[mt], acc[st][mt], 0, 0, 0);
      }
    }
  }
#pragma unroll
  for (int mt = 0; mt < 8; ++mt) {
    float v = -3.4e38f;
#pragma unroll
    for (int st = 0; st < 4; ++st) {
      v = fmaxf(v, fmaxf(fmaxf(acc[st][mt][0], acc[st][mt][1]),
                         fmaxf(acc[st][mt][2], acc[st][mt][3])));
    }
    v = fmaxf(v, __shfl_xor(v, 16, 64));
    v = fmaxf(v, __shfl_xor(v, 32, 64));
    cm[w][mt * 16 + (lane & 15)] = v;
  }
  __syncthreads();
  if (tid < 128) {
    float m = fmaxf(fmaxf(cm[0][tid], cm[1][tid]), fmaxf(cm[2][tid], cm[3][tid]));
    P[(size_t)rblk * M + m0 + tid] = m + bias[m0 + tid];
  }
}

// ---------------------------------------------------------------- reduce P[128][1024] -> gmax[16][1024]
__global__ __launch_bounds__(256) void k_reduce_max(const float* __restrict__ P,
                                                    float* __restrict__ gmax) {
  const int b = blockIdx.x, tid = threadIdx.x;
  for (int c = tid; c < 1024; c += 256) {
    float m = P[(size_t)(b * 8) * 1024 + c];
    for (int rt = 1; rt < 8; ++rt)
      m = fmaxf(m, P[(size_t)(b * 8 + rt) * 1024 + c]);
    gmax[b * 1024 + c] = m;
  }
}

// ---------------------------------------------------------------- head part 1: hid = relu(gmax*W4+b4)
__global__ __launch_bounds__(256) void k_head1(const float* __restrict__ gmax,
                                               const float* __restrict__ w4,
                                               const float* __restrict__ b4,
                                               float* __restrict__ hid) {
  const int b = blockIdx.y, c0 = blockIdx.x * 64;
  const int tid = threadIdx.x;
  const int c = tid & 63, iq = tid >> 6;
  __shared__ float xs[1024];
  __shared__ float red[4][64];
  for (int i = tid; i < 1024; i += 256) xs[i] = gmax[b * 1024 + i];
  __syncthreads();
  float a = 0.f;
  for (int i = iq * 256; i < iq * 256 + 256; ++i)
    a = fmaf(xs[i], w4[(size_t)i * 1024 + c0 + c], a);
  red[iq][c] = a;
  __syncthreads();
  if (tid < 64) {
    float v = red[0][tid] + red[1][tid] + red[2][tid] + red[3][tid];
    hid[b * 1024 + c0 + tid] = fmaxf(v + b4[c0 + tid], 0.f);
  }
}

// ---------------------------------------------------------------- head part 2: out = hid*W5+b5
__global__ __launch_bounds__(256) void k_head2(const float* __restrict__ hid,
                                               const float* __restrict__ w5,
                                               const float* __restrict__ b5,
                                               float* __restrict__ out) {
  const int b = blockIdx.y, c0 = blockIdx.x * 64;
  const int tid = threadIdx.x;
  const int c = tid & 63, iq = tid >> 6;
  __shared__ float xs[1024];
  __shared__ float red[4][64];
  for (int i = tid; i < 1024; i += 256) xs[i] = hid[b * 1024 + i];
  __syncthreads();
  float a = 0.f;
  for (int i = iq * 256; i < iq * 256 + 256; ++i)
    a = fmaf(xs[i], w5[(size_t)i * 512 + c0 + c], a);
  red[iq][c] = a;
  __syncthreads();
  if (tid < 64) {
    float v = red[0][tid] + red[1][tid] + red[2][tid] + red[3][tid];
    out[(size_t)b * 512 + c0 + tid] = v + b5[c0 + tid];
  }
}

// ----------------------------------------------------------------
extern "C" void kernel_launch(void* const* d_in, const int* in_sizes, int n_in,
                              void* d_out, int out_size, void* d_ws, size_t ws_size,
                              hipStream_t stream) {
  (void)in_sizes; (void)n_in; (void)out_size; (void)ws_size;
  const float* x = (const float*)d_in[0];
  const float* w1 = (const float*)d_in[1];  const float* b1 = (const float*)d_in[2];
  const float* w2 = (const float*)d_in[3];  const float* b2 = (const float*)d_in[4];
  const float* w3 = (const float*)d_in[5];  const float* b3 = (const float*)d_in[6];
  const float* g1lw = (const float*)d_in[7];  const float* g1lb = (const float*)d_in[8];
  const float* g1cw = (const float*)d_in[9];  const float* g1cb = (const float*)d_in[10];
  const float* g2lw = (const float*)d_in[11]; const float* g2lb = (const float*)d_in[12];
  const float* g2cw = (const float*)d_in[13]; const float* g2cb = (const float*)d_in[14];
  const float* w4 = (const float*)d_in[15]; const float* b4 = (const float*)d_in[16];
  const float* w5 = (const float*)d_in[17]; const float* b5 = (const float*)d_in[18];
  const float* bn1g = (const float*)d_in[19]; const float* bn1b = (const float*)d_in[20];
  const float* bn1m = (const float*)d_in[21]; const float* bn1v = (const float*)d_in[22];
  const float* bn2g = (const float*)d_in[23]; const float* bn2b = (const float*)d_in[24];
  const float* bn2m = (const float*)d_in[25]; const float* bn2v = (const float*)d_in[26];
  const float* bn3g = (const float*)d_in[27]; const float* bn3b = (const float*)d_in[28];
  const float* bn3m = (const float*)d_in[29]; const float* bn3v = (const float*)d_in[30];

  float* ws = (float*)d_ws;
  size_t off = 0;
  auto alloc = [&](size_t n) { float* p = ws + off; off += (n + 63) & ~(size_t)63; return p; };
  float* slotA = alloc(16u * 2048 * 128);   // h0 then h4 f32
  float* slotB = alloc(16u * 2048 * 64);    // h3 f32
  float* sqv  = alloc(16u * 2048);
  unsigned short* hi_h = (unsigned short*)alloc(16u * 2048 * 64);
  unsigned short* lo_h = (unsigned short*)alloc(16u * 2048 * 64);
  unsigned short* mhi = (unsigned short*)alloc(16u * 2048 * 64);
  unsigned short* mlo = (unsigned short*)alloc(16u * 2048 * 64);
  unsigned short* wthi = (unsigned short*)alloc(65536);
  unsigned short* wtlo = (unsigned short*)alloc(65536);
  float* bc   = alloc(1024);
  float* P    = alloc(128u * 1024);
  float* gm   = alloc(16u * 1024);
  float* hid  = alloc(16u * 1024);

  // 1: knn on xyz + covariance -> h0[B,N,12]
  k_knn1_cov<<<dim3(512, 16), 256, 0, stream>>>(x, slotA);
  // 2: MLP1 -> h3 f32 + bf16 planes
  k_mlp1<<<512, 256, 0, stream>>>(slotA, w1, b1, w2, b2, w3, b3,
                                  bn1g, bn1b, bn1m, bn1v,
                                  bn2g, bn2b, bn2m, bn2v,
                                  bn3g, bn3b, bn3m, bn3v, slotB, hi_h, lo_h);
  // 3: knn(64) fused -> m1 planes
  k_sqnorm<64><<<128, 256, 0, stream>>>(slotB, sqv);
  k_knn_fused<64><<<2048, 1024, 0, stream>>>(hi_h, lo_h, sqv, slotB, mhi, mlo);
  // 4: g1 combined dense 64->128 + relu -> h4 f32 + planes (MFMA)
  k_combine_t<<<32, 256, 0, stream>>>(g1lw, g1lb, g1cw, g1cb, wthi, wtlo, bc, 64, 128);
  k_apply_relu<64, 128><<<dim3(512, 1), 256, 0, stream>>>(
      mhi, mlo, wthi, wtlo, bc, slotA, hi_h, lo_h);
  // 5: knn(128) fused -> m2 planes
  k_sqnorm<128><<<128, 256, 0, stream>>>(slotA, sqv);
  k_knn_fused<128><<<2048, 1024, 0, stream>>>(hi_h, lo_h, sqv, slotA, mhi, mlo);
  // 6: g2 combined dense 128->1024 + colmax -> P (MFMA, W in LDS, 256 rows/block)
  k_combine_t<<<512, 256, 0, stream>>>(g2lw, g2lb, g2cw, g2cb, wthi, wtlo, bc, 128, 1024);
  k_apply_colmax<<<dim3(128, 8), 256, 0, stream>>>(mhi, mlo, wthi, wtlo, bc, P);
  // 7: reduce -> gmax[16][1024]
  k_reduce_max<<<16, 256, 0, stream>>>(P, gm);
  // 8: head -> out[16][512]
  k_head1<<<dim3(16, 16), 256, 0, stream>>>(gm, w4, b4, hid);
  k_head2<<<dim3(8, 16), 256, 0, stream>>>(hid, w5, b5, (float*)d_out);
}

// Round 16
// 814.217 us; speedup vs baseline: 1.4099x; 1.0934x over previous
//
#include <hip/hip_runtime.h>
#include <cstddef>
#include <cstdint>

#define NPTS 2048

typedef short bf16x8 __attribute__((ext_vector_type(8)));
typedef float f32x4 __attribute__((ext_vector_type(4)));

__device__ __forceinline__ unsigned short f2bf(float f) {
  unsigned u = __builtin_bit_cast(unsigned, f);
  unsigned r = u + 0x7fffu + ((u >> 16) & 1u);  // RNE (finite inputs)
  return (unsigned short)(r >> 16);
}
__device__ __forceinline__ float bf2f(unsigned short s) {
  unsigned u = ((unsigned)s) << 16;
  return __builtin_bit_cast(float, u);
}
// float -> order-preserving u32 (handles negatives)
__device__ __forceinline__ unsigned f2sort(float f) {
  unsigned u = __builtin_bit_cast(unsigned, f);
  return u ^ (unsigned)(((int)u >> 31) | 0x80000000);
}

// sorted-4 pool insert (ascending); keys unique
__device__ __forceinline__ void pool_insert(uint64_t k, uint64_t& s0, uint64_t& s1,
                                            uint64_t& s2, uint64_t& s3) {
  s3 = k < s3 ? k : s3;
  uint64_t t;
  t = s2 < s3 ? s2 : s3; s3 = s2 < s3 ? s3 : s2; s2 = t;
  t = s1 < s2 ? s1 : s2; s2 = s1 < s2 ? s2 : s1; s1 = t;
  t = s0 < s1 ? s0 : s1; s1 = s0 < s1 ? s1 : s0; s0 = t;
}

__device__ __forceinline__ int mbcnt64(unsigned long long m) {
  return __builtin_amdgcn_mbcnt_hi((unsigned)(m >> 32),
                                   __builtin_amdgcn_mbcnt_lo((unsigned)m, 0));
}

__device__ __forceinline__ float wave_sum_f32(float v) {
#pragma unroll
  for (int s = 1; s < 64; s <<= 1) v += __shfl_xor(v, s, 64);
  return v;
}

// stable strict-< insert into ascending sorted-8 (u32 key, u32 idx)
__device__ __forceinline__ void ins8(unsigned ku, unsigned ii,
                                     unsigned (&kd)[8], unsigned (&pi)[8]) {
  bool c = ku < kd[7];
  kd[7] = c ? ku : kd[7];
  pi[7] = c ? ii : pi[7];
#pragma unroll
  for (int i = 6; i >= 0; --i) {
    bool s = kd[i + 1] < kd[i];
    unsigned tk = s ? kd[i + 1] : kd[i];
    unsigned tp = s ? pi[i + 1] : pi[i];
    kd[i + 1] = s ? kd[i] : kd[i + 1];
    pi[i + 1] = s ? pi[i] : pi[i + 1];
    kd[i] = tk; pi[i] = tp;
  }
}

// ---------------------------------------------------------------- knn1 + cov (R15-proven)
__global__ __launch_bounds__(256) void k_knn1_cov(const float* __restrict__ x,
                                                  float* __restrict__ h0) {
  const int b = blockIdx.y;
  const int tid = threadIdx.x;
  const int lane = tid & 63;
  const int w = tid >> 6;
  __shared__ float4 xsq[NPTS];
  const float* xb = x + (size_t)b * NPTS * 3;
  for (int i = tid; i < NPTS; i += 256) {
    float a0 = xb[3 * i], a1 = xb[3 * i + 1], a2 = xb[3 * i + 2];
    xsq[i] = make_float4(a0, a1, a2, fmaf(a0, a0, fmaf(a1, a1, a2 * a2)));
  }
  __syncthreads();
  const int nq = blockIdx.x * 4 + w;
  const float4 q4 = xsq[nq];
  const float sqq = q4.w;
  float d[32];
  uint64_t s0 = ~0ull, s1 = ~0ull, s2 = ~0ull, s3 = ~0ull;
#pragma unroll
  for (int j = 0; j < 32; ++j) {
    float4 v = xsq[j * 64 + lane];
    float dot = q4.x * v.x;
    dot = fmaf(q4.y, v.y, dot);
    dot = fmaf(q4.z, v.z, dot);
    float dd = fmaf(-2.f, dot, sqq + v.w);
    d[j] = dd;
    uint64_t k = ((uint64_t)f2sort(dd) << 32) | (unsigned)(j * 64 + lane);
    pool_insert(k, s0, s1, s2, s3);
  }
  const unsigned h0w = (unsigned)(s0 >> 32), m0i = (unsigned)s0;
  const unsigned h1w = (unsigned)(s1 >> 32), m1i = (unsigned)s1;
  const unsigned h2w = (unsigned)(s2 >> 32), m2i = (unsigned)s2;
  const unsigned h3w = (unsigned)(s3 >> 32), m3i = (unsigned)s3;
  unsigned H = 0;
#pragma unroll 1
  for (int bit = 31; bit >= 0; --bit) {
    unsigned tr = H | (1u << bit);
    int c = __popcll(__ballot(h0w < tr)) + __popcll(__ballot(h1w < tr)) +
            __popcll(__ballot(h2w < tr)) + __popcll(__ballot(h3w < tr));
    if (c < 16) H = tr;
  }
  const int cs = __popcll(__ballot(h0w < H)) + __popcll(__ballot(h1w < H)) +
                 __popcll(__ballot(h2w < H)) + __popcll(__ballot(h3w < H));
  const int rneed = 16 - cs;
  const bool e0 = (h0w == H), e1 = (h1w == H), e2 = (h2w == H), e3 = (h3w == H);
  const int gsz = __popcll(__ballot(e0)) + __popcll(__ballot(e1)) +
                  __popcll(__ballot(e2)) + __popcll(__ballot(e3));
  unsigned I = 0xFFFFFFFFu;
  if (gsz > rneed) {
    unsigned Iv = 0;
#pragma unroll 1
    for (int bit = 10; bit >= 0; --bit) {
      unsigned tr = Iv | (1u << bit);
      int c2 = __popcll(__ballot(e0 && m0i < tr)) + __popcll(__ballot(e1 && m1i < tr)) +
               __popcll(__ballot(e2 && m2i < tr)) + __popcll(__ballot(e3 && m3i < tr));
      if (c2 < rneed) Iv = tr;
    }
    I = Iv;
  }
  const bool sel0 = (h0w < H) | (e0 & (m0i <= I));
  const bool sel1 = (h1w < H) | (e1 & (m1i <= I));
  const bool sel2 = (h2w < H) | (e2 & (m2i <= I));
  const bool sel3 = (h3w < H) | (e3 & (m3i <= I));
  const int nsel = (int)sel0 + sel1 + sel2 + sel3;
  float cxx, cxy, cxz, cyy, cyz, czz;
  if (__ballot(nsel == 4) == 0ull) {
    float4 z = make_float4(0.f, 0.f, 0.f, 0.f);
    float4 v0 = sel0 ? xsq[m0i] : z;
    float4 v1 = sel1 ? xsq[m1i] : z;
    float4 v2 = sel2 ? xsq[m2i] : z;
    float4 v3 = sel3 ? xsq[m3i] : z;
    float sx = wave_sum_f32(v0.x + v1.x + v2.x + v3.x);
    float sy = wave_sum_f32(v0.y + v1.y + v2.y + v3.y);
    float sz = wave_sum_f32(v0.z + v1.z + v2.z + v3.z);
    const float mx = sx * 0.0625f, my = sy * 0.0625f, mz = sz * 0.0625f;
    float w0 = sel0 ? 1.f : 0.f, w1 = sel1 ? 1.f : 0.f;
    float w2 = sel2 ? 1.f : 0.f, w3 = sel3 ? 1.f : 0.f;
    float a0x = v0.x - mx, a0y = v0.y - my, a0z = v0.z - mz;
    float a1x = v1.x - mx, a1y = v1.y - my, a1z = v1.z - mz;
    float a2x = v2.x - mx, a2y = v2.y - my, a2z = v2.z - mz;
    float a3x = v3.x - mx, a3y = v3.y - my, a3z = v3.z - mz;
    float pxx = (w0 * a0x) * a0x + (w1 * a1x) * a1x + (w2 * a2x) * a2x + (w3 * a3x) * a3x;
    float pxy = (w0 * a0x) * a0y + (w1 * a1x) * a1y + (w2 * a2x) * a2y + (w3 * a3x) * a3y;
    float pxz = (w0 * a0x) * a0z + (w1 * a1x) * a1z + (w2 * a2x) * a2z + (w3 * a3x) * a3z;
    float pyy = (w0 * a0y) * a0y + (w1 * a1y) * a1y + (w2 * a2y) * a2y + (w3 * a3y) * a3y;
    float pyz = (w0 * a0y) * a0z + (w1 * a1y) * a1z + (w2 * a2y) * a2z + (w3 * a3y) * a3z;
    float pzz = (w0 * a0z) * a0z + (w1 * a1z) * a1z + (w2 * a2z) * a2z + (w3 * a3z) * a3z;
    cxx = wave_sum_f32(pxx); cxy = wave_sum_f32(pxy); cxz = wave_sum_f32(pxz);
    cyy = wave_sum_f32(pyy); cyz = wave_sum_f32(pyz); czz = wave_sum_f32(pzz);
  } else {
    unsigned mask = 0;
    int widx[16];
#pragma unroll 1
    for (int r = 0; r < 16; ++r) {
      float vmin = 3.4e38f;
      int mmin = 0x7fffffff;
#pragma unroll
      for (int j = 0; j < 32; ++j) {
        bool ok = !((mask >> j) & 1u) && (d[j] < vmin);
        if (ok) { vmin = d[j]; mmin = j * 64 + lane; }
      }
#pragma unroll
      for (int s = 1; s < 64; s <<= 1) {
        float ov = __shfl_xor(vmin, s, 64);
        int om = __shfl_xor(mmin, s, 64);
        if (ov < vmin || (ov == vmin && om < mmin)) { vmin = ov; mmin = om; }
      }
      widx[r] = mmin;
      if (lane == (mmin & 63)) mask |= 1u << (mmin >> 6);
    }
    float sx = 0, sy = 0, sz = 0;
#pragma unroll
    for (int r = 0; r < 16; ++r) {
      float4 v = xsq[widx[r]];
      sx += v.x; sy += v.y; sz += v.z;
    }
    const float mx = sx * 0.0625f, my = sy * 0.0625f, mz = sz * 0.0625f;
    cxx = cxy = cxz = cyy = cyz = czz = 0.f;
#pragma unroll
    for (int r = 0; r < 16; ++r) {
      float4 v = xsq[widx[r]];
      float ax = v.x - mx, ay = v.y - my, az = v.z - mz;
      cxx = fmaf(ax, ax, cxx); cxy = fmaf(ax, ay, cxy); cxz = fmaf(ax, az, cxz);
      cyy = fmaf(ay, ay, cyy); cyz = fmaf(ay, az, cyz); czz = fmaf(az, az, czz);
    }
  }
  if (lane == 0) {
    float* o = h0 + ((size_t)b * NPTS + nq) * 12;
    *(float4*)&o[0] = make_float4(q4.x, q4.y, q4.z, cxx);
    *(float4*)&o[4] = make_float4(cxy, cxz, cxy, cyy);
    *(float4*)&o[8] = make_float4(cyz, cxz, cyz, czz);
  }
}

// ---------------------------------------------------------------- MLP1 (12->12->64->64, BN folded) + bf16 plane epilogue
__global__ __launch_bounds__(256) void k_mlp1(
    const float* __restrict__ h0,
    const float* __restrict__ w1, const float* __restrict__ cb1,
    const float* __restrict__ w2, const float* __restrict__ cb2,
    const float* __restrict__ w3, const float* __restrict__ cb3,
    const float* __restrict__ bn1g, const float* __restrict__ bn1b,
    const float* __restrict__ bn1m, const float* __restrict__ bn1v,
    const float* __restrict__ bn2g, const float* __restrict__ bn2b,
    const float* __restrict__ bn2m, const float* __restrict__ bn2v,
    const float* __restrict__ bn3g, const float* __restrict__ bn3b,
    const float* __restrict__ bn3m, const float* __restrict__ bn3v,
    float* __restrict__ h3out,
    unsigned short* __restrict__ h3hi, unsigned short* __restrict__ h3lo) {
  __shared__ float W1[144], W2[768], W3[4096];
  __shared__ float S1[12], F1[12], S2[64], F2[64], S3[64], F3[64];
  __shared__ float h0s[64][12];
  __shared__ float A2[64][65];
  const int tid = threadIdx.x;
  for (int i = tid; i < 144; i += 256) W1[i] = w1[i];
  for (int i = tid; i < 768; i += 256) W2[i] = w2[i];
  for (int i = tid; i < 4096; i += 256) W3[i] = w3[i];
  if (tid < 12) {
    float s = bn1g[tid] * rsqrtf(bn1v[tid] + 1e-3f);
    S1[tid] = s; F1[tid] = (cb1[tid] - bn1m[tid]) * s + bn1b[tid];
  }
  if (tid < 64) {
    float s2 = bn2g[tid] * rsqrtf(bn2v[tid] + 1e-3f);
    S2[tid] = s2; F2[tid] = (cb2[tid] - bn2m[tid]) * s2 + bn2b[tid];
    float s3 = bn3g[tid] * rsqrtf(bn3v[tid] + 1e-3f);
    S3[tid] = s3; F3[tid] = (cb3[tid] - bn3m[tid]) * s3 + bn3b[tid];
  }
  const int p0 = blockIdx.x * 64;
  for (int i = tid; i < 64 * 12; i += 256)
    h0s[i / 12][i % 12] = h0[(size_t)p0 * 12 + i];
  __syncthreads();
  const int pl = tid >> 2;
  const int q = tid & 3;
  float v1[12];
#pragma unroll
  for (int o = 0; o < 12; ++o) {
    float a = 0.f;
#pragma unroll
    for (int i = 0; i < 12; ++i) a = fmaf(h0s[pl][i], W1[i * 12 + o], a);
    v1[o] = fmaxf(fmaf(a, S1[o], F1[o]), 0.f);
  }
#pragma unroll
  for (int o = 0; o < 16; ++o) {
    int oo = q * 16 + o;
    float a = 0.f;
#pragma unroll
    for (int i = 0; i < 12; ++i) a = fmaf(v1[i], W2[i * 64 + oo], a);
    A2[pl][oo] = fmaxf(fmaf(a, S2[oo], F2[oo]), 0.f);
  }
  __syncthreads();
  float acc[16];
#pragma unroll
  for (int o = 0; o < 16; ++o) acc[o] = 0.f;
  for (int i = 0; i < 64; ++i) {
    float xv = A2[pl][i];
#pragma unroll
    for (int o = 0; o < 16; ++o) acc[o] = fmaf(xv, W3[i * 64 + q * 16 + o], acc[o]);
  }
  float vals[16];
#pragma unroll
  for (int o = 0; o < 16; ++o) {
    int oo = q * 16 + o;
    vals[o] = fmaxf(fmaf(acc[o], S3[oo], F3[oo]), 0.f);
  }
  const size_t rowo = (size_t)(p0 + pl) * 64 + q * 16;
  float* orow = h3out + rowo;
#pragma unroll
  for (int o4 = 0; o4 < 4; ++o4)
    *(float4*)&orow[4 * o4] = make_float4(vals[4 * o4], vals[4 * o4 + 1],
                                          vals[4 * o4 + 2], vals[4 * o4 + 3]);
  bf16x8 hv0, hv1, lv0, lv1;
#pragma unroll
  for (int o = 0; o < 8; ++o) {
    unsigned short hb = f2bf(vals[o]);
    hv0[o] = (short)hb; lv0[o] = (short)f2bf(vals[o] - bf2f(hb));
    unsigned short hb1 = f2bf(vals[8 + o]);
    hv1[o] = (short)hb1; lv1[o] = (short)f2bf(vals[8 + o] - bf2f(hb1));
  }
  *(bf16x8*)&h3hi[rowo] = hv0; *(bf16x8*)&h3hi[rowo + 8] = hv1;
  *(bf16x8*)&h3lo[rowo] = lv0; *(bf16x8*)&h3lo[rowo + 8] = lv1;
}

// ---------------------------------------------------------------- sq norms
template <int C>
__global__ __launch_bounds__(256) void k_sqnorm(const float* __restrict__ h,
                                                float* __restrict__ sq) {
  const int p = blockIdx.x * 256 + threadIdx.x;
  const float* row = h + (size_t)p * C;
  float a = 0.f;
#pragma unroll
  for (int i = 0; i < C; ++i) a = fmaf(row[i], row[i], a);
  sq[p] = a;
}

// ---------------------------------------------------------------- knn via D^T MFMA + online register pools (no LDS, no barrier)
// 256 thr / 4 waves; wave = 16 queries (B-operand) x 2048 cands (A-operand).
// Lane owns query col lane&15; 2 interleaved sorted-8 pools; exact unless a
// pool saturates (P~2.6e-4/query) -> flag for gated R13 cleanup pass.
template <int C>
__global__ __launch_bounds__(256, 2) void k_knn_pool(
    const unsigned short* __restrict__ hi, const unsigned short* __restrict__ lo,
    const float* __restrict__ sq, const float* __restrict__ h,
    unsigned short* __restrict__ mhi, unsigned short* __restrict__ mlo,
    int* __restrict__ flags) {
  constexpr int KK = C / 32;
  constexpr int DL = C / 4;
  const int tid = threadIdx.x, lane = tid & 63, w = tid >> 6;
  const int f = blockIdx.x;
  const int g = ((f & 7) << 6) | (f >> 3);  // 512 blocks; XCD owns 2 batches
  const int b = g >> 5;
  const int q0 = ((g & 31) * 4 + w) * 16;
  const size_t base = (size_t)b * NPTS * C;
  const float* __restrict__ sqb = sq + (size_t)b * NPTS;
  const int r = lane & 15, g4 = lane >> 4, ks = g4 * 8;
  // cache query (B) fragments for the whole K-loop
  bf16x8 bh[KK], bl[KK];
#pragma unroll
  for (int k4 = 0; k4 < KK; ++k4) {
    bh[k4] = *(const bf16x8*)&hi[base + (size_t)(q0 + r) * C + k4 * 32 + ks];
    bl[k4] = *(const bf16x8*)&lo[base + (size_t)(q0 + r) * C + k4 * 32 + ks];
  }
  const float sqq = sqb[q0 + r];
  unsigned kdA[8], piA[8], kdB[8], piB[8];
#pragma unroll
  for (int i = 0; i < 8; ++i) {
    kdA[i] = 0xFFFFFFFFu; piA[i] = 0xFFFFFFFFu;
    kdB[i] = 0xFFFFFFFFu; piB[i] = 0xFFFFFFFFu;
  }
#pragma unroll 1
  for (int t = 0; t < 128; ++t) {
    f32x4 acc = (f32x4){0.f, 0.f, 0.f, 0.f};
    const unsigned short* ap_h = hi + base + (size_t)(t * 16 + r) * C + ks;
    const unsigned short* ap_l = lo + base + (size_t)(t * 16 + r) * C + ks;
#pragma unroll
    for (int k4 = 0; k4 < KK; ++k4) {
      bf16x8 ah = *(const bf16x8*)(ap_h + k4 * 32);
      bf16x8 al = *(const bf16x8*)(ap_l + k4 * 32);
      // product order matches R13: (c_h q_h), (c_l q_h)=old(q_h c_l), (c_h q_l)=old(q_l c_h)
      acc = __builtin_amdgcn_mfma_f32_16x16x32_bf16(ah, bh[k4], acc, 0, 0, 0);
      acc = __builtin_amdgcn_mfma_f32_16x16x32_bf16(al, bh[k4], acc, 0, 0, 0);
      acc = __builtin_amdgcn_mfma_f32_16x16x32_bf16(ah, bl[k4], acc, 0, 0, 0);
    }
    float4 sqc = *(const float4*)&sqb[t * 16 + g4 * 4];
    const unsigned ib = (unsigned)(t * 16 + g4 * 4);
    {
      float dd = fmaf(-2.f, acc[0], sqq + sqc.x);
      ins8(f2sort(dd), ib + 0, kdA, piA);
    }
    {
      float dd = fmaf(-2.f, acc[1], sqq + sqc.y);
      ins8(f2sort(dd), ib + 1, kdB, piB);
    }
    {
      float dd = fmaf(-2.f, acc[2], sqq + sqc.z);
      ins8(f2sort(dd), ib + 2, kdA, piA);
    }
    {
      float dd = fmaf(-2.f, acc[3], sqq + sqc.w);
      ins8(f2sort(dd), ib + 3, kdB, piB);
    }
  }
  // 16-round extraction within 4-lane query groups + gather-max
  const float* __restrict__ hbp = h + base;
  int cntA = 0, cntB = 0;
  float gm[DL];
#pragma unroll
  for (int j = 0; j < DL; ++j) gm[j] = -3.4e38f;
#pragma unroll 1
  for (int rr = 0; rr < 16; ++rr) {
    uint64_t kA = ((uint64_t)kdA[0] << 32) | piA[0];
    uint64_t kB = ((uint64_t)kdB[0] << 32) | piB[0];
    uint64_t kc = kA < kB ? kA : kB;
    uint64_t km = kc;
    uint64_t o1 = __shfl_xor((unsigned long long)km, 16, 64);
    km = o1 < km ? o1 : km;
    o1 = __shfl_xor((unsigned long long)km, 32, 64);
    km = o1 < km ? o1 : km;
    const bool exA = (kA == km);
    const bool exB = (kB == km);
    cntA += exA ? 1 : 0;
    cntB += exB ? 1 : 0;
#pragma unroll
    for (int i = 0; i < 7; ++i) {
      kdA[i] = exA ? kdA[i + 1] : kdA[i]; piA[i] = exA ? piA[i + 1] : piA[i];
      kdB[i] = exB ? kdB[i + 1] : kdB[i]; piB[i] = exB ? piB[i + 1] : piB[i];
    }
    kdA[7] = exA ? 0xFFFFFFFFu : kdA[7]; piA[7] = exA ? 0xFFFFFFFFu : piA[7];
    kdB[7] = exB ? 0xFFFFFFFFu : kdB[7]; piB[7] = exB ? 0xFFFFFFFFu : piB[7];
    const unsigned m = (unsigned)km;  // uniform within 4-lane group
    const float* row = hbp + (size_t)m * C + g4 * DL;
#pragma unroll
    for (int j4 = 0; j4 < DL / 4; ++j4) {
      float4 v = *(const float4*)&row[j4 * 4];
      gm[j4 * 4 + 0] = fmaxf(gm[j4 * 4 + 0], v.x);
      gm[j4 * 4 + 1] = fmaxf(gm[j4 * 4 + 1], v.y);
      gm[j4 * 4 + 2] = fmaxf(gm[j4 * 4 + 2], v.z);
      gm[j4 * 4 + 3] = fmaxf(gm[j4 * 4 + 3], v.w);
    }
  }
  // overflow flag per query (group-or over its 4 lanes)
  const bool of = (cntA == 8) || (cntB == 8);
  unsigned long long bal = __ballot(of);
  unsigned qm = (unsigned)((bal >> r) | (bal >> (r + 16)) | (bal >> (r + 32)) |
                           (bal >> (r + 48)));
  if (g4 == 0) flags[b * NPTS + q0 + r] = (int)(qm & 1u);
  // write planes: lane covers dims [g4*DL, g4*DL+DL) of query q0+r
  const size_t orow = base + (size_t)(q0 + r) * C + g4 * DL;
#pragma unroll
  for (int j8 = 0; j8 < DL / 8; ++j8) {
    bf16x8 hv, lv;
#pragma unroll
    for (int jj = 0; jj < 8; ++jj) {
      float v = gm[j8 * 8 + jj];
      unsigned short hb = f2bf(v);
      hv[jj] = (short)hb;
      lv[jj] = (short)f2bf(v - bf2f(hb));
    }
    *(bf16x8*)&mhi[orow + j8 * 8] = hv;
    *(bf16x8*)&mlo[orow + j8 * 8] = lv;
  }
}

// ---------------------------------------------------------------- gated cleanup: R13-proven fused knn, runs only on flagged tiles
#define DSTRIDE 2052
template <int C>
__global__ __launch_bounds__(1024, 4) void k_knn_fused(
    const unsigned short* __restrict__ hi, const unsigned short* __restrict__ lo,
    const float* __restrict__ sq, const float* __restrict__ h,
    unsigned short* __restrict__ mhi, unsigned short* __restrict__ mlo,
    const int* __restrict__ flags) {
  __shared__ float dmat[16][DSTRIDE];
  __shared__ unsigned nidx[16][16];
  __shared__ int anyf;
  const int tid = threadIdx.x, lane = tid & 63, w = tid >> 6;
  const int f = blockIdx.x;
  const int g = ((f & 7) << 8) | (f >> 3);
  const int b = g >> 7;
  const int q0 = (g & 127) * 16;
  if (tid == 0) {
    int s = 0;
#pragma unroll 1
    for (int i = 0; i < 16; ++i) s |= flags[b * NPTS + q0 + i];
    anyf = s;
  }
  __syncthreads();
  if (!anyf) return;
  const size_t base = (size_t)b * NPTS * C;
  const float* __restrict__ sqb = sq + (size_t)b * NPTS;
  const int r = lane & 15, ks = (lane >> 4) * 8;
  const unsigned short* Ah = hi + base + (size_t)(q0 + r) * C + ks;
  const unsigned short* Al = lo + base + (size_t)(q0 + r) * C + ks;
  float sqq[4];
#pragma unroll
  for (int r2 = 0; r2 < 4; ++r2) sqq[r2] = sqb[q0 + (lane >> 4) * 4 + r2];
  {
    const int m0 = w * 128;
    const unsigned short* Bh = hi + base + (size_t)(m0 + r) * C + ks;
    const unsigned short* Bl = lo + base + (size_t)(m0 + r) * C + ks;
    f32x4 acc[8];
#pragma unroll
    for (int s = 0; s < 8; ++s) acc[s] = (f32x4){0.f, 0.f, 0.f, 0.f};
#pragma unroll
    for (int kk = 0; kk < C; kk += 32) {
      bf16x8 ah = *(const bf16x8*)(Ah + kk);
      bf16x8 al = *(const bf16x8*)(Al + kk);
#pragma unroll
      for (int s = 0; s < 8; ++s) {
        bf16x8 bhv = *(const bf16x8*)(Bh + (size_t)s * 16 * C + kk);
        bf16x8 blv = *(const bf16x8*)(Bl + (size_t)s * 16 * C + kk);
        acc[s] = __builtin_amdgcn_mfma_f32_16x16x32_bf16(ah, bhv, acc[s], 0, 0, 0);
        acc[s] = __builtin_amdgcn_mfma_f32_16x16x32_bf16(ah, blv, acc[s], 0, 0, 0);
        acc[s] = __builtin_amdgcn_mfma_f32_16x16x32_bf16(al, bhv, acc[s], 0, 0, 0);
      }
    }
#pragma unroll
    for (int s = 0; s < 8; ++s) {
      const int col = m0 + s * 16 + (lane & 15);
      float smc = sqb[col];
#pragma unroll
      for (int r2 = 0; r2 < 4; ++r2)
        dmat[(lane >> 4) * 4 + r2][col] = fmaf(-2.f, acc[s][r2], sqq[r2] + smc);
    }
  }
  __syncthreads();
  const float* __restrict__ hbp = h + base;
  const int q = q0 + w;
  uint64_t s0 = ~0ull, s1 = ~0ull, s2 = ~0ull, s3 = ~0ull;
#pragma unroll
  for (int t = 0; t < 8; ++t) {
    float4 dv = *(const float4*)&dmat[w][t * 256 + 4 * lane];
    const unsigned mb = (unsigned)(t * 256 + 4 * lane);
    pool_insert(((uint64_t)f2sort(dv.x) << 32) | (mb + 0), s0, s1, s2, s3);
    pool_insert(((uint64_t)f2sort(dv.y) << 32) | (mb + 1), s0, s1, s2, s3);
    pool_insert(((uint64_t)f2sort(dv.z) << 32) | (mb + 2), s0, s1, s2, s3);
    pool_insert(((uint64_t)f2sort(dv.w) << 32) | (mb + 3), s0, s1, s2, s3);
  }
  const unsigned h0 = (unsigned)(s0 >> 32), m0i = (unsigned)s0;
  const unsigned h1 = (unsigned)(s1 >> 32), m1i = (unsigned)s1;
  const unsigned h2 = (unsigned)(s2 >> 32), m2i = (unsigned)s2;
  const unsigned h3 = (unsigned)(s3 >> 32), m3i = (unsigned)s3;
  unsigned H = 0;
#pragma unroll 1
  for (int bit = 31; bit >= 0; --bit) {
    unsigned tr = H | (1u << bit);
    int c = __popcll(__ballot(h0 < tr)) + __popcll(__ballot(h1 < tr)) +
            __popcll(__ballot(h2 < tr)) + __popcll(__ballot(h3 < tr));
    if (c < 16) H = tr;
  }
  const int cs = __popcll(__ballot(h0 < H)) + __popcll(__ballot(h1 < H)) +
                 __popcll(__ballot(h2 < H)) + __popcll(__ballot(h3 < H));
  const int rneed = 16 - cs;
  const bool e0 = (h0 == H), e1 = (h1 == H), e2 = (h2 == H), e3 = (h3 == H);
  const int gsz = __popcll(__ballot(e0)) + __popcll(__ballot(e1)) +
                  __popcll(__ballot(e2)) + __popcll(__ballot(e3));
  unsigned I = 0xFFFFFFFFu;
  if (gsz > rneed) {
    unsigned Iv = 0;
#pragma unroll 1
    for (int bit = 10; bit >= 0; --bit) {
      unsigned tr = Iv | (1u << bit);
      int c2 = __popcll(__ballot(e0 && m0i < tr)) + __popcll(__ballot(e1 && m1i < tr)) +
               __popcll(__ballot(e2 && m2i < tr)) + __popcll(__ballot(e3 && m3i < tr));
      if (c2 < rneed) Iv = tr;
    }
    I = Iv;
  }
  const bool sel0 = (h0 < H) | (e0 & (m0i <= I));
  const bool sel1 = (h1 < H) | (e1 & (m1i <= I));
  const bool sel2 = (h2 < H) | (e2 & (m2i <= I));
  const bool sel3 = (h3 < H) | (e3 & (m3i <= I));
  const int nsel = (int)sel0 + sel1 + sel2 + sel3;
  float g0 = -3.4e38f, g1 = -3.4e38f;
  if (__ballot(nsel == 4) == 0ull) {
    unsigned long long bm;
    int bpos = 0;
    bm = __ballot(sel0); if (sel0) nidx[w][bpos + mbcnt64(bm)] = m0i; bpos += __popcll(bm);
    bm = __ballot(sel1); if (sel1) nidx[w][bpos + mbcnt64(bm)] = m1i; bpos += __popcll(bm);
    bm = __ballot(sel2); if (sel2) nidx[w][bpos + mbcnt64(bm)] = m2i; bpos += __popcll(bm);
    bm = __ballot(sel3); if (sel3) nidx[w][bpos + mbcnt64(bm)] = m3i;
#pragma unroll
    for (int rr = 0; rr < 16; ++rr) {
      unsigned m = nidx[w][rr];
      const float* row = hbp + (size_t)m * C;
      g0 = fmaxf(g0, row[lane]);
      if (C == 128) g1 = fmaxf(g1, row[64 + lane]);
    }
  } else {
    unsigned mask = 0u;
#pragma unroll 1
    for (int rr = 0; rr < 16; ++rr) {
      float vmin = 3.4e38f;
      int mmin = 0x7fffffff;
#pragma unroll
      for (int j = 0; j < 32; ++j) {
        const int m = (j >> 2) * 256 + 4 * lane + (j & 3);
        float dj = dmat[w][m];
        bool ok = !((mask >> j) & 1u) && (dj < vmin);
        if (ok) { vmin = dj; mmin = m; }
      }
#pragma unroll
      for (int s = 1; s < 64; s <<= 1) {
        float ov = __shfl_xor(vmin, s, 64);
        int om = __shfl_xor(mmin, s, 64);
        if (ov < vmin || (ov == vmin && om < mmin)) { vmin = ov; mmin = om; }
      }
      if (lane == ((mmin >> 2) & 63)) mask |= 1u << (((mmin >> 8) << 2) | (mmin & 3));
      const float* row = hbp + (size_t)mmin * C;
      g0 = fmaxf(g0, row[lane]);
      if (C == 128) g1 = fmaxf(g1, row[64 + lane]);
    }
  }
  const size_t orow = base + (size_t)q * C;
  unsigned short h0b = f2bf(g0);
  mhi[orow + lane] = h0b;
  mlo[orow + lane] = f2bf(g0 - bf2f(h0b));
  if (C == 128) {
    unsigned short h1b = f2bf(g1);
    mhi[orow + 64 + lane] = h1b;
    mlo[orow + 64 + lane] = f2bf(g1 - bf2f(h1b));
  }
}

// ---------------------------------------------------------------- combine denses -> W^T bf16 planes + bias
__global__ __launch_bounds__(256) void k_combine_t(const float* __restrict__ lw,
                                                   const float* __restrict__ lb,
                                                   const float* __restrict__ cw,
                                                   const float* __restrict__ cb,
                                                   unsigned short* __restrict__ wthi,
                                                   unsigned short* __restrict__ wtlo,
                                                   float* __restrict__ bc, int K, int M) {
  const int id = blockIdx.x * 256 + threadIdx.x;
  if (id < K * M) {
    int i = id / M, o = id % M;
    float a = 0.f;
    for (int k = 0; k < K; ++k) a = fmaf(lw[i * K + k], cw[k * M + o], a);
    unsigned short hb = f2bf(a);
    wthi[(size_t)o * K + i] = hb;
    wtlo[(size_t)o * K + i] = f2bf(a - bf2f(hb));
  }
  if (id < M) {
    float a = cb[id];
    for (int k = 0; k < K; ++k) a = fmaf(lb[k], cw[k * M + id], a);
    bc[id] = a;
  }
}

// ---------------------------------------------------------------- MFMA apply RELU (g1): 64 rows/block
template <int K, int M>
__global__ __launch_bounds__(256) void k_apply_relu(
    const unsigned short* __restrict__ Ah, const unsigned short* __restrict__ Al,
    const unsigned short* __restrict__ Wh, const unsigned short* __restrict__ Wl,
    const float* __restrict__ bias, float* __restrict__ fout,
    unsigned short* __restrict__ phi, unsigned short* __restrict__ plo) {
  const int tid = threadIdx.x, lane = tid & 63, w = tid >> 6;
  const int q0 = blockIdx.x * 64 + w * 16;
  const int m0 = blockIdx.y * 128;
  const int r = lane & 15, ks = (lane >> 4) * 8;
  const unsigned short* ap_h = Ah + (size_t)(q0 + r) * K + ks;
  const unsigned short* ap_l = Al + (size_t)(q0 + r) * K + ks;
  const unsigned short* bp_h = Wh + (size_t)(m0 + r) * K + ks;
  const unsigned short* bp_l = Wl + (size_t)(m0 + r) * K + ks;
  f32x4 acc[8];
#pragma unroll
  for (int mt = 0; mt < 8; ++mt) acc[mt] = (f32x4){0.f, 0.f, 0.f, 0.f};
#pragma unroll
  for (int kk = 0; kk < K; kk += 32) {
    bf16x8 ah = *(const bf16x8*)(ap_h + kk);
    bf16x8 al = *(const bf16x8*)(ap_l + kk);
#pragma unroll
    for (int mt = 0; mt < 8; ++mt) {
      bf16x8 bh = *(const bf16x8*)(bp_h + (size_t)mt * 16 * K + kk);
      bf16x8 bl = *(const bf16x8*)(bp_l + (size_t)mt * 16 * K + kk);
      acc[mt] = __builtin_amdgcn_mfma_f32_16x16x32_bf16(ah, bh, acc[mt], 0, 0, 0);
      acc[mt] = __builtin_amdgcn_mfma_f32_16x16x32_bf16(ah, bl, acc[mt], 0, 0, 0);
      acc[mt] = __builtin_amdgcn_mfma_f32_16x16x32_bf16(al, bh, acc[mt], 0, 0, 0);
    }
  }
#pragma unroll
  for (int mt = 0; mt < 8; ++mt) {
    const int col = m0 + mt * 16 + (lane & 15);
    const float bv = bias[col];
#pragma unroll
    for (int r2 = 0; r2 < 4; ++r2) {
      const int row = q0 + (lane >> 4) * 4 + r2;
      float v = fmaxf(acc[mt][r2] + bv, 0.f);
      const size_t idx = (size_t)row * M + col;
      fout[idx] = v;
      unsigned short hb = f2bf(v);
      phi[idx] = hb;
      plo[idx] = f2bf(v - bf2f(hb));
    }
  }
}

// ---------------------------------------------------------------- MFMA apply COLMAX (g2): 256 rows/block, W staged in LDS
#define WSTRIDE 136
__global__ __launch_bounds__(256, 2) void k_apply_colmax(
    const unsigned short* __restrict__ Ah, const unsigned short* __restrict__ Al,
    const unsigned short* __restrict__ Wh, const unsigned short* __restrict__ Wl,
    const float* __restrict__ bias, float* __restrict__ P) {
  constexpr int K = 128, M = 1024;
  __shared__ unsigned short Bh_s[128 * WSTRIDE];
  __shared__ unsigned short Bl_s[128 * WSTRIDE];
  __shared__ float cm[4][128];
  const int tid = threadIdx.x, lane = tid & 63, w = tid >> 6;
  const int rblk = blockIdx.x;
  const int m0 = blockIdx.y * 128;
  const int r = lane & 15, ks = (lane >> 4) * 8;
  for (int i = tid; i < 128 * 16; i += 256) {
    int row = i >> 4, c8 = (i & 15) * 8;
    *(bf16x8*)&Bh_s[row * WSTRIDE + c8] = *(const bf16x8*)&Wh[(size_t)(m0 + row) * K + c8];
    *(bf16x8*)&Bl_s[row * WSTRIDE + c8] = *(const bf16x8*)&Wl[(size_t)(m0 + row) * K + c8];
  }
  __syncthreads();
  const int q0 = rblk * 256 + w * 64;
  f32x4 acc[4][8];
#pragma unroll
  for (int st = 0; st < 4; ++st)
#pragma unroll
    for (int mt = 0; mt < 8; ++mt) acc[st][mt] = (f32x4){0.f, 0.f, 0.f, 0.f};
#pragma unroll
  for (int kk = 0; kk < K; kk += 32) {
    bf16x8 bh[8], bl[8];
#pragma unroll
    for (int mt = 0; mt < 8; ++mt) {
      bh[mt] = *(const bf16x8*)&Bh_s[(mt * 16 + r) * WSTRIDE + ks + kk];
      bl[mt] = *(const bf16x8*)&Bl_s[(mt * 16 + r) * WSTRIDE + ks + kk];
    }
#pragma unroll
    for (int st = 0; st < 4; ++st) {
      const unsigned short* ap_h = Ah + (size_t)(q0 + st * 16 + r) * K + ks + kk;
      const unsigned short* ap_l = Al + (size_t)(q0 + st * 16 + r) * K + ks + kk;
      bf16x8 ah = *(const bf16x8*)ap_h;
      bf16x8 al = *(const bf16x8*)ap_l;
#pragma unroll
      for (int mt = 0; mt < 8; ++mt) {
        acc[st][mt] = __builtin_amdgcn_mfma_f32_16x16x32_bf16(ah, bh[mt], acc[st][mt], 0, 0, 0);
        acc[st][mt] = __builtin_amdgcn_mfma_f32_16x16x32_bf16(ah, bl[mt], acc[st][mt], 0, 0, 0);
        acc[st][mt] = __builtin_amdgcn_mfma_f32_16x16x32_bf16(al, bh[mt], acc[st][mt], 0, 0, 0);
      }
    }
  }
#pragma unroll
  for (int mt = 0; mt < 8; ++mt) {
    float v = -3.4e38f;
#pragma unroll
    for (int st = 0; st < 4; ++st) {
      v = fmaxf(v, fmaxf(fmaxf(acc[st][mt][0], acc[st][mt][1]),
                         fmaxf(acc[st][mt][2], acc[st][mt][3])));
    }
    v = fmaxf(v, __shfl_xor(v, 16, 64));
    v = fmaxf(v, __shfl_xor(v, 32, 64));
    cm[w][mt * 16 + (lane & 15)] = v;
  }
  __syncthreads();
  if (tid < 128) {
    float m = fmaxf(fmaxf(cm[0][tid], cm[1][tid]), fmaxf(cm[2][tid], cm[3][tid]));
    P[(size_t)rblk * M + m0 + tid] = m + bias[m0 + tid];
  }
}

// ---------------------------------------------------------------- reduce P[128][1024] -> gmax[16][1024]
__global__ __launch_bounds__(256) void k_reduce_max(const float* __restrict__ P,
                                                    float* __restrict__ gmax) {
  const int b = blockIdx.x, tid = threadIdx.x;
  for (int c = tid; c < 1024; c += 256) {
    float m = P[(size_t)(b * 8) * 1024 + c];
    for (int rt = 1; rt < 8; ++rt)
      m = fmaxf(m, P[(size_t)(b * 8 + rt) * 1024 + c]);
    gmax[b * 1024 + c] = m;
  }
}

// ---------------------------------------------------------------- head part 1: hid = relu(gmax*W4+b4)
__global__ __launch_bounds__(256) void k_head1(const float* __restrict__ gmax,
                                               const float* __restrict__ w4,
                                               const float* __restrict__ b4,
                                               float* __restrict__ hid) {
  const int b = blockIdx.y, c0 = blockIdx.x * 64;
  const int tid = threadIdx.x;
  const int c = tid & 63, iq = tid >> 6;
  __shared__ float xs[1024];
  __shared__ float red[4][64];
  for (int i = tid; i < 1024; i += 256) xs[i] = gmax[b * 1024 + i];
  __syncthreads();
  float a = 0.f;
  for (int i = iq * 256; i < iq * 256 + 256; ++i)
    a = fmaf(xs[i], w4[(size_t)i * 1024 + c0 + c], a);
  red[iq][c] = a;
  __syncthreads();
  if (tid < 64) {
    float v = red[0][tid] + red[1][tid] + red[2][tid] + red[3][tid];
    hid[b * 1024 + c0 + tid] = fmaxf(v + b4[c0 + tid], 0.f);
  }
}

// ---------------------------------------------------------------- head part 2: out = hid*W5+b5
__global__ __launch_bounds__(256) void k_head2(const float* __restrict__ hid,
                                               const float* __restrict__ w5,
                                               const float* __restrict__ b5,
                                               float* __restrict__ out) {
  const int b = blockIdx.y, c0 = blockIdx.x * 64;
  const int tid = threadIdx.x;
  const int c = tid & 63, iq = tid >> 6;
  __shared__ float xs[1024];
  __shared__ float red[4][64];
  for (int i = tid; i < 1024; i += 256) xs[i] = hid[b * 1024 + i];
  __syncthreads();
  float a = 0.f;
  for (int i = iq * 256; i < iq * 256 + 256; ++i)
    a = fmaf(xs[i], w5[(size_t)i * 512 + c0 + c], a);
  red[iq][c] = a;
  __syncthreads();
  if (tid < 64) {
    float v = red[0][tid] + red[1][tid] + red[2][tid] + red[3][tid];
    out[(size_t)b * 512 + c0 + tid] = v + b5[c0 + tid];
  }
}

// ----------------------------------------------------------------
extern "C" void kernel_launch(void* const* d_in, const int* in_sizes, int n_in,
                              void* d_out, int out_size, void* d_ws, size_t ws_size,
                              hipStream_t stream) {
  (void)in_sizes; (void)n_in; (void)out_size; (void)ws_size;
  const float* x = (const float*)d_in[0];
  const float* w1 = (const float*)d_in[1];  const float* b1 = (const float*)d_in[2];
  const float* w2 = (const float*)d_in[3];  const float* b2 = (const float*)d_in[4];
  const float* w3 = (const float*)d_in[5];  const float* b3 = (const float*)d_in[6];
  const float* g1lw = (const float*)d_in[7];  const float* g1lb = (const float*)d_in[8];
  const float* g1cw = (const float*)d_in[9];  const float* g1cb = (const float*)d_in[10];
  const float* g2lw = (const float*)d_in[11]; const float* g2lb = (const float*)d_in[12];
  const float* g2cw = (const float*)d_in[13]; const float* g2cb = (const float*)d_in[14];
  const float* w4 = (const float*)d_in[15]; const float* b4 = (const float*)d_in[16];
  const float* w5 = (const float*)d_in[17]; const float* b5 = (const float*)d_in[18];
  const float* bn1g = (const float*)d_in[19]; const float* bn1b = (const float*)d_in[20];
  const float* bn1m = (const float*)d_in[21]; const float* bn1v = (const float*)d_in[22];
  const float* bn2g = (const float*)d_in[23]; const float* bn2b = (const float*)d_in[24];
  const float* bn2m = (const float*)d_in[25]; const float* bn2v = (const float*)d_in[26];
  const float* bn3g = (const float*)d_in[27]; const float* bn3b = (const float*)d_in[28];
  const float* bn3m = (const float*)d_in[29]; const float* bn3v = (const float*)d_in[30];

  float* ws = (float*)d_ws;
  size_t off = 0;
  auto alloc = [&](size_t n) { float* p = ws + off; off += (n + 63) & ~(size_t)63; return p; };
  float* slotA = alloc(16u * 2048 * 128);   // h0 then h4 f32
  float* slotB = alloc(16u * 2048 * 64);    // h3 f32
  float* sqv  = alloc(16u * 2048);
  unsigned short* hi_h = (unsigned short*)alloc(16u * 2048 * 64);
  unsigned short* lo_h = (unsigned short*)alloc(16u * 2048 * 64);
  unsigned short* mhi = (unsigned short*)alloc(16u * 2048 * 64);
  unsigned short* mlo = (unsigned short*)alloc(16u * 2048 * 64);
  unsigned short* wthi = (unsigned short*)alloc(65536);
  unsigned short* wtlo = (unsigned short*)alloc(65536);
  float* bc   = alloc(1024);
  float* P    = alloc(128u * 1024);
  float* gm   = alloc(16u * 1024);
  float* hid  = alloc(16u * 1024);
  int* flags  = (int*)alloc(16u * 2048);

  // 1: knn on xyz + covariance -> h0[B,N,12]
  k_knn1_cov<<<dim3(512, 16), 256, 0, stream>>>(x, slotA);
  // 2: MLP1 -> h3 f32 + bf16 planes
  k_mlp1<<<512, 256, 0, stream>>>(slotA, w1, b1, w2, b2, w3, b3,
                                  bn1g, bn1b, bn1m, bn1v,
                                  bn2g, bn2b, bn2m, bn2v,
                                  bn3g, bn3b, bn3m, bn3v, slotB, hi_h, lo_h);
  // 3: knn(64) pool kernel + gated exact cleanup -> m1 planes
  k_sqnorm<64><<<128, 256, 0, stream>>>(slotB, sqv);
  k_knn_pool<64><<<512, 256, 0, stream>>>(hi_h, lo_h, sqv, slotB, mhi, mlo, flags);
  k_knn_fused<64><<<2048, 1024, 0, stream>>>(hi_h, lo_h, sqv, slotB, mhi, mlo, flags);
  // 4: g1 combined dense 64->128 + relu -> h4 f32 + planes (MFMA)
  k_combine_t<<<32, 256, 0, stream>>>(g1lw, g1lb, g1cw, g1cb, wthi, wtlo, bc, 64, 128);
  k_apply_relu<64, 128><<<dim3(512, 1), 256, 0, stream>>>(
      mhi, mlo, wthi, wtlo, bc, slotA, hi_h, lo_h);
  // 5: knn(128) pool kernel + gated exact cleanup -> m2 planes
  k_sqnorm<128><<<128, 256, 0, stream>>>(slotA, sqv);
  k_knn_pool<128><<<512, 256, 0, stream>>>(hi_h, lo_h, sqv, slotA, mhi, mlo, flags);
  k_knn_fused<128><<<2048, 1024, 0, stream>>>(hi_h, lo_h, sqv, slotA, mhi, mlo, flags);
  // 6: g2 combined dense 128->1024 + colmax -> P (MFMA, W in LDS, 256 rows/block)
  k_combine_t<<<512, 256, 0, stream>>>(g2lw, g2lb, g2cw, g2cb, wthi, wtlo, bc, 128, 1024);
  k_apply_colmax<<<dim3(128, 8), 256, 0, stream>>>(mhi, mlo, wthi, wtlo, bc, P);
  // 7: reduce -> gmax[16][1024]
  k_reduce_max<<<16, 256, 0, stream>>>(P, gm);
  // 8: head -> out[16][512]
  k_head1<<<dim3(16, 16), 256, 0, stream>>>(gm, w4, b4, hid);
  k_head2<<<dim3(8, 16), 256, 0, stream>>>(hid, w5, b5, (float*)d_out);
}